// Round 10
// baseline (725.957 us; speedup 1.0000x reference)
//
#include <hip/hip_runtime.h>
#include <hip/hip_bf16.h>
#include <math.h>

#define EPS_BN 1e-5f

typedef __bf16 bf16x8 __attribute__((ext_vector_type(8)));
typedef float f32x4 __attribute__((ext_vector_type(4)));

// async global->LDS, 16B per lane. LDS dest must be wave-uniform base + lane*16
__device__ __forceinline__ void gl2lds16(const void* g, void* l) {
  __builtin_amdgcn_global_load_lds(
      (const __attribute__((address_space(1))) unsigned int*)g,
      (__attribute__((address_space(3))) unsigned int*)l, 16, 0, 0);
}

// ============================================================================
// conv1 + bias + BN + ReLU + maxpool2: x[CH,1,48,48] fp32 ->
// out1p PADDED bf16 NHWC [CH][26][26][256] zero halo.
// One block per (image, 6-output-row band). Thread = channel.
// ============================================================================
__global__ __launch_bounds__(256) void k_conv1(
    const float* __restrict__ x, const float* __restrict__ w,
    const float* __restrict__ cb, const float* __restrict__ g,
    const float* __restrict__ bb, const float* __restrict__ m,
    const float* __restrict__ v, __hip_bfloat16* __restrict__ out1p) {
  __shared__ float xp[14 * 50];
  const int bq = blockIdx.x;
  const int b = bq >> 2, q = bq & 3;  // band q: output rows 6q..6q+5
  const int t = threadIdx.x;
  __hip_bfloat16* ob = out1p + (size_t)b * (26 * 26 * 256);
  const __hip_bfloat16 z = __float2bfloat16(0.f);
  if (q == 0)
    for (int i = t; i < 26 * 256; i += 256) ob[i] = z;
  if (q == 3)
    for (int i = t; i < 26 * 256; i += 256) ob[25 * 26 * 256 + i] = z;
  for (int i = t; i < 6 * 2 * 256; i += 256) {
    int r = 1 + 6 * q + (i >> 9), side = (i >> 8) & 1, c = i & 255;
    ob[(r * 26 + side * 25) * 256 + c] = z;
  }
  for (int i = t; i < 14 * 50; i += 256) xp[i] = 0.f;
  __syncthreads();
  const float* xb = x + (size_t)b * 2304;
  for (int i = t; i < 14 * 48; i += 256) {
    int rr = i / 48, c = i - rr * 48;
    int gr = 12 * q - 1 + rr;
    if (gr >= 0 && gr < 48) xp[rr * 50 + c + 1] = xb[gr * 48 + c];
  }
  __syncthreads();
  float wr[9];
#pragma unroll
  for (int i = 0; i < 9; i++) wr[i] = w[t * 9 + i];
  const float scale = g[t] * rsqrtf(v[t] + EPS_BN);
  const float bias = (cb[t] - m[t]) * scale + bb[t];
#pragma unroll
  for (int ohl = 0; ohl < 6; ohl++) {
    const int r0 = 2 * ohl;
    float2 c01[4];
#pragma unroll
    for (int r = 0; r < 4; r++) c01[r] = *(const float2*)&xp[(r0 + r) * 50];
#pragma unroll 4
    for (int ow = 0; ow < 24; ow++) {
      float2 c23[4];
#pragma unroll
      for (int r = 0; r < 4; r++)
        c23[r] = *(const float2*)&xp[(r0 + r) * 50 + 2 * ow + 2];
      float s4[4];
      int ii = 0;
#pragma unroll
      for (int dh = 0; dh < 2; dh++)
#pragma unroll
        for (int dw = 0; dw < 2; dw++, ii++) {
          float s = 0.f;
#pragma unroll
          for (int kh = 0; kh < 3; kh++) {
            const int rr = dh + kh;
            float col[4] = {c01[rr].x, c01[rr].y, c23[rr].x, c23[rr].y};
#pragma unroll
            for (int kw = 0; kw < 3; kw++)
              s = fmaf(col[dw + kw], wr[kh * 3 + kw], s);
          }
          s4[ii] = s * scale + bias;  // BN before pool (scale may be negative)
        }
      float mx = fmaxf(fmaxf(s4[0], s4[1]), fmaxf(s4[2], s4[3]));
      ob[((6 * q + ohl + 1) * 26 + (ow + 1)) * 256 + t] =
          __float2bfloat16(fmaxf(mx, 0.f));
#pragma unroll
      for (int r = 0; r < 4; r++) c01[r] = c23[r];
    }
  }
}

// ============================================================================
// Weight prep: w [OC][IC][3][3] fp32 -> bf16 [9][IC/32][OC][4][8]:
// one wave B-load = 64 lanes x 16B = one CONTIGUOUS 1KB segment.
// ============================================================================
template <int IC, int OC>
__global__ void k_twi(const float* __restrict__ w,
                      __hip_bfloat16* __restrict__ wt) {
  int idx = blockIdx.x * 256 + threadIdx.x;
  if (idx >= 9 * IC * OC) return;
  int icr = idx & 7;
  int lhi = (idx >> 3) & 3;
  int oc = (idx >> 5) % OC;
  int rest = (idx >> 5) / OC;
  int kb = rest % (IC / 32);
  int p = rest / (IC / 32);
  int ic = kb * 32 + lhi * 8 + icr;
  wt[idx] = __float2bfloat16(w[(oc * IC + ic) * 9 + p]);
}

// zero the halo of padded out2p [CH][14][14][128] bf16 (conv2 writes interior)
__global__ void k_halo2(__hip_bfloat16* __restrict__ out2p) {
  int b = blockIdx.x, t = threadIdx.x;
  __hip_bfloat16* ob = out2p + (size_t)b * (14 * 14 * 128);
  const __hip_bfloat16 z = __float2bfloat16(0.f);
  for (int i = t; i < 14 * 128; i += 256) {
    ob[i] = z;
    ob[13 * 14 * 128 + i] = z;
  }
  for (int i = t; i < 12 * 2 * 128; i += 256) {
    int r = 1 + (i >> 8), side = (i >> 7) & 1, c = i & 127;
    ob[(r * 14 + side * 13) * 128 + c] = z;
  }
}

// ============================================================================
// MFMA implicit-GEMM conv + bias + BN + ReLU + fused maxpool2 (bf16, fp32 acc)
// in:  padded bf16 NHWC [nb][HP][HP][IC]  (HP = HW+2, zero halo)
// wt:  bf16 [9][IC/32][OC][4][8] (wave-contiguous B fragments)
//
// 4 waves share M = MTW*16 rows; each wave owns OC/4 columns.
// K-loop = NSTEP unrolled steps with a DEPTH-4 register ring on B.
// Key scheduling facts (R9 post-mortem):
//  - __launch_bounds__(256,3): VGPR+AGPR <= 170 -> 3 waves/SIMD (12/CU).
//    R9's 172 regs capped residency at 2/SIMD and erased the ring's gain.
//  - next-window DMA is issued at step 13, AFTER that step's ring refill:
//    the vmcnt queue is ordered, so a DMA issued at stage start forced the
//    first post-DMA B-consume to drain ~900cyc of DMA latency mid-stage.
//    Late placement => in-stage consumes only ever wait on <=4-step-old
//    B loads; the DMA completes under 4 steps + barrier (multi-wave overlap).
// A window in LDS via global_load_lds DMA, double-buffered, 1 barrier/stage;
// xor-swizzled slots keep fragment reads <=2-way bank aliased (free).
// conv2: HW=24 IC=256 OC=128 MTW=6 -> padded bf16 NHWC [14][14][128]
// conv3: HW=12 IC=128 OC=64  MTW=3 -> fp32 NCHW [64][6][6]
// ============================================================================
template <int HW, int IC, int OC, int MTW, bool NCHW_OUT>
__global__ __launch_bounds__(256, 3) void k_mconv(
    const __hip_bfloat16* __restrict__ in, const __hip_bfloat16* __restrict__ wt,
    const float* __restrict__ cb, const float* __restrict__ gg,
    const float* __restrict__ bbv, const float* __restrict__ bm,
    const float* __restrict__ bv, void* __restrict__ outp) {
  constexpr int HP = HW + 2;
  constexpr int MT = MTW * 16;      // block M rows (96 / 48)
  constexpr int ROWS = MT / HW;     // output h-rows per block (4 / 4)
  constexpr int WR = ROWS + 2;      // input window rows (6 / 6)
  constexpr int TILES = HW / ROWS;  // blocks per image (6 / 3)
  constexpr int WN = OC / 4;        // wave N width (32 / 16)
  constexpr int NF = WN / 16;       // n-frags per wave (2 / 1)
  constexpr int CP = HP;            // window cols (26 / 14)
  constexpr int NCH = WR * CP * 8;  // real 16B slots per window
  constexpr int NCHP = (NCH + 255) & ~255;
  constexpr int NLD = NCHP / 256;   // DMA chunks per thread (5 / 3)
  constexpr int NSTG = IC / 64;     // kc stages (4 / 2)
  constexpr int ABUF = NCHP * 16;   // bytes per window (20480 / 12288)
  constexpr int KG = IC / 32;
  constexpr int EPITCH = OC + 1;
  constexpr int EBYTES = 48 * EPITCH * 4;
  constexpr int SMB = (2 * ABUF) > EBYTES ? (2 * ABUF) : EBYTES;
  constexpr int NSTEP = NSTG * 18;  // 72 / 36
  constexpr int D = 4;              // B prefetch depth (register ring)

  __shared__ __align__(16) char smraw[SMB];
  float* se = (float*)smraw;  // epilogue tile (aliases windows, dead by then)

  const int tid = threadIdx.x;
  const int wn = tid >> 6, ln = tid & 63;
  const int lhi = ln >> 4, llo = ln & 15;

  const int b = blockIdx.x / TILES;
  const int T = blockIdx.x - b * TILES;
  const int h0 = T * ROWS;

  const __hip_bfloat16* inb = in + (size_t)b * HP * HP * IC;

  // staging source map: slot ci = tid + i*256 -> (r, c, kgslot), kg swizzled
  int srcoff[NLD];
#pragma unroll
  for (int i = 0; i < NLD; i++) {
    int ci = tid + i * 256;
    if (ci >= NCH) ci = NCH - 1;  // pad slots: dup read, dest lands in pad
    int kgslot = ci & 7;
    int rest = ci >> 3;
    int c = rest % CP;
    int r = rest / CP;
    int kg = kgslot ^ (c & 7);
    srcoff[i] = ((h0 + r) * HP + c) * IC + kg * 8;  // elements; +kc at use
  }
  // A-frag read precompute: spatial slot base & col (for swizzle) per mt
  int spb[MTW], wlv[MTW];
#pragma unroll
  for (int mt = 0; mt < MTW; mt++) {
    int m = mt * 16 + llo;
    int hl = m / HW, wl = m % HW;
    spb[mt] = (hl * CP + wl) * 8;
    wlv[mt] = wl;
  }
  const __hip_bfloat16* wtb = wt + (wn * WN + llo) * 32 + lhi * 8;

  f32x4 acc[MTW][NF];
  const f32x4 fz = {0.f, 0.f, 0.f, 0.f};
#pragma unroll
  for (int i = 0; i < MTW; i++)
#pragma unroll
    for (int j = 0; j < NF; j++) acc[i][j] = fz;

  // prologue: DMA stage 0 into window 0; preload B ring for steps 0..D-1
#pragma unroll
  for (int i = 0; i < NLD; i++)
    gl2lds16(inb + srcoff[i], smraw + (tid + i * 256) * 16);
  bf16x8 bq[D][NF];
#pragma unroll
  for (int d = 0; d < D; d++) {
    const int sg = d / 18, pg = (d % 18) >> 1, kf = d & 1;
#pragma unroll
    for (int j = 0; j < NF; j++)
      bq[d][j] = *(const bf16x8*)(wtb +
                                  (size_t)((pg * KG + sg * 2 + kf) * OC) * 32 +
                                  j * 512);
  }
  __syncthreads();

#pragma unroll
  for (int s = 0; s < NSTG; s++) {
    const char* cw = smraw + (s & 1) * ABUF;
#pragma unroll
    for (int t = 0; t < 18; t++) {
      const int g = s * 18 + t;
      const int p = t >> 1, ks = t & 1;
      const int ph = p / 3, pw = p % 3;
      const int kg = ks * 4 + lhi;
      // consume bq[g%D]
#pragma unroll
      for (int mt = 0; mt < MTW; mt++) {
        int slot = spb[mt] + (ph * CP + pw) * 8 + (kg ^ ((wlv[mt] + pw) & 7));
        bf16x8 af = *(const bf16x8*)(cw + slot * 16);
#pragma unroll
        for (int j = 0; j < NF; j++)
          acc[mt][j] = __builtin_amdgcn_mfma_f32_16x16x32_bf16(
              af, bq[g % D][j], acc[mt][j], 0, 0, 0);
      }
      // refill ring slot for step g+D (SSA: safe vs the consume above)
      if (g + D < NSTEP) {
        const int gf = g + D;
        const int sg = gf / 18, pg = (gf % 18) >> 1, kf = gf & 1;
#pragma unroll
        for (int j = 0; j < NF; j++)
          bq[gf % D][j] =
              *(const bf16x8*)(wtb +
                               (size_t)((pg * KG + sg * 2 + kf) * OC) * 32 +
                               j * 512);
      }
      // issue next-window DMA LATE (after this step's ring refill): in-stage
      // B consumes then never wait on DMA in the ordered vmcnt queue.
      if (t == 13 && s + 1 < NSTG) {
        char* nb = smraw + ((s + 1) & 1) * ABUF;
#pragma unroll
        for (int i = 0; i < NLD; i++)
          gl2lds16(inb + srcoff[i] + (s + 1) * 64, nb + (tid + i * 256) * 16);
      }
    }
    __syncthreads();  // window s reads done; DMA for s+1 drained
  }

  // ---- epilogue in 48-row passes: BN+ReLU -> se [48][EPITCH], pool, store
  constexpr int NPASS = MTW / 3;  // 2 / 1
  constexpr int HR = 48 / HW;     // h-rows per pass (2 / 4)
  constexpr int OHP = HR / 2;     // pooled rows per pass (1 / 2)
  constexpr int OHW = HW / 2;
  constexpr int NP = OHP * OHW * OC;
#pragma unroll
  for (int pz = 0; pz < NPASS; pz++) {
    if (pz) __syncthreads();
#pragma unroll
    for (int j = 0; j < NF; j++) {
      int n = wn * WN + j * 16 + llo;
      float scale = gg[n] * rsqrtf(bv[n] + EPS_BN);
      float bias = (cb[n] - bm[n]) * scale + bbv[n];
#pragma unroll
      for (int mtl = 0; mtl < 3; mtl++)
#pragma unroll
        for (int r = 0; r < 4; r++) {
          int mrow = mtl * 16 + lhi * 4 + r;
          se[mrow * EPITCH + n] =
              fmaxf(acc[pz * 3 + mtl][j][r] * scale + bias, 0.f);
        }
    }
    __syncthreads();
    for (int sI = tid; sI < NP; sI += 256) {
      int n = sI % OC;
      int ow = (sI / OC) % OHW;
      int ohl = sI / (OC * OHW);
      int mloc = (2 * ohl) * HW + 2 * ow;
      float x0 = se[mloc * EPITCH + n];
      float x1 = se[(mloc + 1) * EPITCH + n];
      float x2 = se[(mloc + HW) * EPITCH + n];
      float x3 = se[(mloc + HW + 1) * EPITCH + n];
      float mx = fmaxf(fmaxf(x0, x1), fmaxf(x2, x3));
      int oh = (h0 >> 1) + pz * OHP + ohl;
      if (NCHW_OUT) {
        ((float*)outp)[(((size_t)b * OC + n) * OHW + oh) * OHW + ow] = mx;
      } else {  // padded bf16 NHWC [OHW+2][OHW+2][OC], interior at +1
        ((__hip_bfloat16*)
             outp)[(((size_t)b * (OHW + 2) + oh + 1) * (OHW + 2) + ow + 1) *
                       OC +
                   n] = __float2bfloat16(mx);
      }
    }
  }
}

// ============================================================================
// FC chain collapse (pure linear): W32 = att_w@fc2_w; W_eff = W32@fc1_w
// (stored TRANSPOSED [2304][64] for coalesced k_q reads);
// b_eff = W32@fc1_b + att_w@fc2_b + att_b; q = out4 @ W_eff^T + b_eff
// ============================================================================
__global__ void k_w32(const float* __restrict__ A3, const float* __restrict__ A2,
                      float* __restrict__ W32) {
  int idx = blockIdx.x * 256 + threadIdx.x;  // 64*512
  int r = idx >> 9, c = idx & 511;
  float s = 0.f;
  for (int k = 0; k < 256; k++) s = fmaf(A3[r * 256 + k], A2[k * 512 + c], s);
  W32[idx] = s;
}
__global__ void k_weff(const float* __restrict__ W32, const float* __restrict__ A1,
                       float* __restrict__ Wet) {
  int idx = blockIdx.x * 256 + threadIdx.x;  // 64*2304
  int r = idx / 2304, c = idx - r * 2304;
  float s = 0.f;
  for (int k = 0; k < 512; k++) s = fmaf(W32[r * 512 + k], A1[k * 2304 + c], s);
  Wet[c * 64 + r] = s;  // transposed store
}
__global__ void k_beff(const float* __restrict__ W32, const float* __restrict__ b1,
                       const float* __restrict__ A3, const float* __restrict__ b2,
                       const float* __restrict__ b3, float* __restrict__ be) {
  int r = threadIdx.x;  // 64
  float s = b3[r];
  for (int k = 0; k < 512; k++) s = fmaf(W32[r * 512 + k], b1[k], s);
  for (int k = 0; k < 256; k++) s = fmaf(A3[r * 256 + k], b2[k], s);
  be[r] = s;
}
__global__ __launch_bounds__(256) void k_q(const float* __restrict__ X,
                                           const float* __restrict__ Wet,
                                           const float* __restrict__ be,
                                           float* __restrict__ q) {
  int n = threadIdx.x & 63;
  int b = blockIdx.x * 4 + (threadIdx.x >> 6);
  const float* xr = X + (size_t)b * 2304;
  float s = be[n];
  for (int k = 0; k < 2304; k++) s = fmaf(xr[k], Wet[k * 64 + n], s);
  q[b * 64 + n] = s;
}

// ============================================================================
// Spatial attention + fc3. One wave per image. out3 NCHW fp32 [512][64][6][6].
// ============================================================================
__global__ __launch_bounds__(64) void k_attn(
    const float* __restrict__ out3, const float* __restrict__ q,
    const float* __restrict__ w3, const float* __restrict__ b3,
    float* __restrict__ out) {
  int b = blockIdx.x, t = threadIdx.x;
  __shared__ float ql[64], sc[36], gm[64];
  const float* o3 = out3 + (size_t)b * 2304;
  ql[t] = q[b * 64 + t];
  __syncthreads();
  float s = -INFINITY;
  if (t < 36) {
    float acc = 0.f;
    for (int c = 0; c < 64; c++) acc = fmaf(o3[c * 36 + t], ql[c], acc);
    s = acc;
  }
  float mx = s;
  for (int off = 32; off >= 1; off >>= 1) mx = fmaxf(mx, __shfl_xor(mx, off));
  float e = (t < 36) ? expf(s - mx) : 0.f;
  float sum = e;
  for (int off = 32; off >= 1; off >>= 1) sum += __shfl_xor(sum, off);
  if (t < 36) sc[t] = e / sum;
  __syncthreads();
  float gv = 0.f;
  for (int hw = 0; hw < 36; hw++) gv = fmaf(o3[t * 36 + hw], sc[hw], gv);
  gm[t] = gv;
  __syncthreads();
  if (t < 7) {
    float acc = b3[t];
    for (int c = 0; c < 64; c++) acc = fmaf(w3[t * 64 + c], gm[c], acc);
    out[b * 7 + t] = acc;
  }
}

// ============================================================================
extern "C" void kernel_launch(void* const* d_in, const int* in_sizes, int n_in,
                              void* d_out, int out_size, void* d_ws,
                              size_t ws_size, hipStream_t stream) {
  const float* x    = (const float*)d_in[0];
  const float* c1w  = (const float*)d_in[1];
  const float* c1b  = (const float*)d_in[2];
  const float* g1   = (const float*)d_in[3];
  const float* bb1  = (const float*)d_in[4];
  const float* m1   = (const float*)d_in[5];
  const float* v1   = (const float*)d_in[6];
  const float* c2w  = (const float*)d_in[7];
  const float* c2b  = (const float*)d_in[8];
  const float* g2   = (const float*)d_in[9];
  const float* bb2  = (const float*)d_in[10];
  const float* m2   = (const float*)d_in[11];
  const float* v2   = (const float*)d_in[12];
  const float* c3w  = (const float*)d_in[13];
  const float* c3b  = (const float*)d_in[14];
  const float* g3   = (const float*)d_in[15];
  const float* bb3  = (const float*)d_in[16];
  const float* m3   = (const float*)d_in[17];
  const float* v3   = (const float*)d_in[18];
  const float* fc1w = (const float*)d_in[19];
  const float* fc1b = (const float*)d_in[20];
  const float* fc2w = (const float*)d_in[21];
  const float* fc2b = (const float*)d_in[22];
  const float* attw = (const float*)d_in[23];
  const float* attb = (const float*)d_in[24];
  const float* fc3w = (const float*)d_in[25];
  const float* fc3b = (const float*)d_in[26];

  // chunking: per-chunk bf16 bufs out1p CH*173056 + out2p CH*25088 elems
  const size_t PER_CHUNK = (173056ULL + 25088ULL) * 2;  // bytes per image
  const size_t PERSIST = 4718592 + 589824 + 147456 + 131072 + 589824 + 256 +
                         131072 + 8192;  // out3+wt2+wt3+W32+Wet+be+q+align
  int CH = 512;
  while (CH > 8 && (size_t)CH * PER_CHUNK + PERSIST > ws_size) CH >>= 1;
  const int NCHK = 512 / CH;

  char* base = (char*)d_ws;
  size_t off = 0;
  auto alloc = [&](size_t nbytes) -> void* {
    void* p = base + off;
    off = (off + nbytes + 255) & ~(size_t)255;
    return p;
  };
  __hip_bfloat16* out1p = (__hip_bfloat16*)alloc((size_t)CH * 173056 * 2);
  __hip_bfloat16* out2p = (__hip_bfloat16*)alloc((size_t)CH * 25088 * 2);
  float* out3          = (float*)alloc(4718592);
  __hip_bfloat16* wt2  = (__hip_bfloat16*)alloc(589824);
  __hip_bfloat16* wt3  = (__hip_bfloat16*)alloc(147456);
  float* W32           = (float*)alloc(131072);
  float* Wet           = (float*)alloc(589824);
  float* be            = (float*)alloc(256);
  float* q             = (float*)alloc(131072);

  // weight prep + FC collapse
  k_twi<256, 128><<<1152, 256, 0, stream>>>(c2w, wt2);
  k_twi<128, 64><<<288, 256, 0, stream>>>(c3w, wt3);
  k_w32<<<128, 256, 0, stream>>>(attw, fc2w, W32);
  k_weff<<<576, 256, 0, stream>>>(W32, fc1w, Wet);
  k_beff<<<1, 64, 0, stream>>>(W32, fc1b, attw, fc2b, attb, be);

  for (int c = 0; c < NCHK; c++) {
    const float* xc = x + (size_t)c * CH * 2304;
    float* o3c = out3 + (size_t)c * CH * 2304;
    k_conv1<<<CH * 4, 256, 0, stream>>>(xc, c1w, c1b, g1, bb1, m1, v1, out1p);
    k_halo2<<<CH, 256, 0, stream>>>(out2p);
    k_mconv<24, 256, 128, 6, false>
        <<<CH * 6, 256, 0, stream>>>(out1p, wt2, c2b, g2, bb2, m2, v2, out2p);
    k_mconv<12, 128, 64, 3, true>
        <<<CH * 3, 256, 0, stream>>>(out2p, wt3, c3b, g3, bb3, m3, v3, o3c);
  }

  k_q<<<128, 256, 0, stream>>>(out3, Wet, be, q);
  k_attn<<<512, 64, 0, stream>>>(out3, q, fc3w, fc3b, (float*)d_out);
}

// Round 11
// 482.778 us; speedup vs baseline: 1.5037x; 1.5037x over previous
//
#include <hip/hip_runtime.h>
#include <hip/hip_bf16.h>
#include <math.h>

#define EPS_BN 1e-5f

typedef __bf16 bf16x8 __attribute__((ext_vector_type(8)));
typedef float f32x4 __attribute__((ext_vector_type(4)));
typedef float f32x2 __attribute__((ext_vector_type(2)));

// async global->LDS, 16B per lane. LDS dest must be wave-uniform base + lane*16
__device__ __forceinline__ void gl2lds16(const void* g, void* l) {
  __builtin_amdgcn_global_load_lds(
      (const __attribute__((address_space(1))) unsigned int*)g,
      (__attribute__((address_space(3))) unsigned int*)l, 16, 0, 0);
}

// ============================================================================
// conv1 + bias + BN + ReLU + maxpool2: x[CH,1,48,48] fp32 ->
// out1p PADDED bf16 NHWC [CH][26][26][256] zero halo.
// One block per (image, 6-output-row band). Thread = channel.
// Inner math packed as f32x2 over the two dw positions -> v_pk_fma_f32:
// 18 pk-FMA vs 36 scalar FMA per pooled output (conv1 is VALU-floor bound).
// ALSO fused: zeroing of out2p's halo (conv3 reads it; conv2 writes interior).
// ============================================================================
__global__ __launch_bounds__(256) void k_conv1(
    const float* __restrict__ x, const float* __restrict__ w,
    const float* __restrict__ cb, const float* __restrict__ g,
    const float* __restrict__ bb, const float* __restrict__ m,
    const float* __restrict__ v, __hip_bfloat16* __restrict__ out1p,
    __hip_bfloat16* __restrict__ out2p) {
  __shared__ float xp[14 * 50];
  const int bq = blockIdx.x;
  const int b = bq >> 2, q = bq & 3;  // band q: output rows 6q..6q+5
  const int t = threadIdx.x;
  __hip_bfloat16* ob = out1p + (size_t)b * (26 * 26 * 256);
  const __hip_bfloat16 z = __float2bfloat16(0.f);
  // out1p halo zeroing split across bands
  if (q == 0)
    for (int i = t; i < 26 * 256; i += 256) ob[i] = z;
  if (q == 3)
    for (int i = t; i < 26 * 256; i += 256) ob[25 * 26 * 256 + i] = z;
  for (int i = t; i < 6 * 2 * 256; i += 256) {
    int r = 1 + 6 * q + (i >> 9), side = (i >> 8) & 1, c = i & 255;
    ob[(r * 26 + side * 25) * 256 + c] = z;
  }
  // fused out2p halo zeroing (quartered across bands)
  {
    __hip_bfloat16* o2 = out2p + (size_t)b * (14 * 14 * 128);
    if (q == 0)
      for (int i = t; i < 14 * 128; i += 256) o2[i] = z;
    if (q == 1)
      for (int i = t; i < 14 * 128; i += 256) o2[13 * 14 * 128 + i] = z;
    if (q == 2)
      for (int i = t; i < 6 * 2 * 128; i += 256) {
        int r = 1 + (i >> 8), side = (i >> 7) & 1, c = i & 127;
        o2[(r * 14 + side * 13) * 128 + c] = z;
      }
    if (q == 3)
      for (int i = t; i < 6 * 2 * 128; i += 256) {
        int r = 7 + (i >> 8), side = (i >> 7) & 1, c = i & 127;
        o2[(r * 14 + side * 13) * 128 + c] = z;
      }
  }
  for (int i = t; i < 14 * 50; i += 256) xp[i] = 0.f;
  __syncthreads();
  const float* xb = x + (size_t)b * 2304;
  for (int i = t; i < 14 * 48; i += 256) {
    int rr = i / 48, c = i - rr * 48;
    int gr = 12 * q - 1 + rr;
    if (gr >= 0 && gr < 48) xp[rr * 50 + c + 1] = xb[gr * 48 + c];
  }
  __syncthreads();
  float wr[9];
#pragma unroll
  for (int i = 0; i < 9; i++) wr[i] = w[t * 9 + i];
  const float scale = g[t] * rsqrtf(v[t] + EPS_BN);
  const float bias = (cb[t] - m[t]) * scale + bb[t];
#pragma unroll
  for (int ohl = 0; ohl < 6; ohl++) {
    const int r0 = 2 * ohl;
    f32x2 c01[4];
#pragma unroll
    for (int r = 0; r < 4; r++) c01[r] = *(const f32x2*)&xp[(r0 + r) * 50];
#pragma unroll 4
    for (int ow = 0; ow < 24; ow++) {
      f32x2 c23[4];
#pragma unroll
      for (int r = 0; r < 4; r++)
        c23[r] = *(const f32x2*)&xp[(r0 + r) * 50 + 2 * ow + 2];
      // window cols 2ow..2ow+3 = [c01.x c01.y c23.x c23.y] per row.
      // packed over dw: pair(kw) = {col[kw], col[kw+1]}
      f32x2 s2a = 0.f, s2b = 0.f;  // dh = 0, 1
#pragma unroll
      for (int r = 0; r < 4; r++) {
        f32x2 p0 = c01[r], p2 = c23[r];
        f32x2 p1 = {p0.y, p2.x};
        if (r <= 2) {  // dh=0, kh=r
          s2a += p0 * wr[r * 3 + 0];
          s2a += p1 * wr[r * 3 + 1];
          s2a += p2 * wr[r * 3 + 2];
        }
        if (r >= 1) {  // dh=1, kh=r-1
          s2b += p0 * wr[(r - 1) * 3 + 0];
          s2b += p1 * wr[(r - 1) * 3 + 1];
          s2b += p2 * wr[(r - 1) * 3 + 2];
        }
      }
      // BN before pool (scale may be negative)
      f32x2 b0 = s2a * scale + bias;
      f32x2 b1 = s2b * scale + bias;
      float mx = fmaxf(fmaxf(b0.x, b0.y), fmaxf(b1.x, b1.y));
      ob[((6 * q + ohl + 1) * 26 + (ow + 1)) * 256 + t] =
          __float2bfloat16(fmaxf(mx, 0.f));
#pragma unroll
      for (int r = 0; r < 4; r++) c01[r] = c23[r];
    }
  }
}

// ============================================================================
// Fused weight prep (one launch):
//   blocks [0,1152):       conv2 w -> bf16 [9][IC/8][OC][8]   (IC=256 OC=128)
//   blocks [1152,1440):    conv3 w -> bf16 [9][IC/8][OC][8]   (IC=128 OC=64)
//   blocks [1440,1568):    W32 = att_w[64,256] @ fc2_w[256,512]
//   block  1568:           b_eff = att_w@(fc2_w@fc1_b + fc2_b) + att_b
// ============================================================================
__global__ void k_prep(const float* __restrict__ c2w,
                       __hip_bfloat16* __restrict__ wt2,
                       const float* __restrict__ c3w,
                       __hip_bfloat16* __restrict__ wt3,
                       const float* __restrict__ attw,
                       const float* __restrict__ fc2w, float* __restrict__ W32,
                       const float* __restrict__ fc1b,
                       const float* __restrict__ fc2b,
                       const float* __restrict__ attb, float* __restrict__ be) {
  const int blk = blockIdx.x, tid = threadIdx.x;
  if (blk < 1152) {  // twi conv2: [9][32][128][8]
    int idx = blk * 256 + tid;
    int icr = idx & 7;
    int oc = (idx >> 3) & 127;
    int rest = idx >> 10;
    int icg = rest & 31;
    int p = rest >> 5;
    wt2[idx] = __float2bfloat16(c2w[(oc * 256 + icg * 8 + icr) * 9 + p]);
  } else if (blk < 1440) {  // twi conv3: [9][16][64][8]
    int idx = (blk - 1152) * 256 + tid;
    int icr = idx & 7;
    int oc = (idx >> 3) & 63;
    int rest = idx >> 9;
    int icg = rest & 15;
    int p = rest >> 4;
    wt3[idx] = __float2bfloat16(c3w[(oc * 128 + icg * 8 + icr) * 9 + p]);
  } else if (blk < 1568) {  // W32
    int idx = (blk - 1440) * 256 + tid;
    int r = idx >> 9, c = idx & 511;
    float s = 0.f;
    for (int k = 0; k < 256; k++)
      s = fmaf(attw[r * 256 + k], fc2w[k * 512 + c], s);
    W32[idx] = s;
  } else {  // b_eff
    __shared__ float t1[256];
    float s = fc2b[tid];
    for (int k = 0; k < 512; k++) s = fmaf(fc2w[tid * 512 + k], fc1b[k], s);
    t1[tid] = s;
    __syncthreads();
    if (tid < 64) {
      float r = attb[tid];
      for (int k = 0; k < 256; k++) r = fmaf(attw[tid * 256 + k], t1[k], r);
      be[tid] = r;
    }
  }
}

// ============================================================================
// MFMA implicit-GEMM conv + bias + BN + ReLU + fused maxpool2 (bf16, fp32 acc)
// in:  padded bf16 NHWC [nb][HP][HP][IC]  (HP = HW+2, zero halo)
// wt:  bf16 [9][IC/8][OC][8]
// ===> R6 structure (best measured: 165us, 44% of bf16 dense peak). Ring
// (R9) and forced occupancy bounds (R10) both measured as regressions.
// A window in LDS via global_load_lds DMA, double-buffered, 1 barrier/stage.
// CP = HP exactly; 16B slot (r,c,kgslot) at (r*CP+c)*8 + kgslot, holding
// kg = kgslot ^ (c&7) (xor swizzle: fragment reads <=2-way aliased = free).
// B fragments per-lane direct from global (L2-resident weights).
// XCD swizzle: all TILES tiles of an image map to one XCD (L2 halo reuse).
// conv2: HW=24 IC=256 OC=128 waves 2x2 -> padded bf16 NHWC [14][14][128]
// conv3: HW=12 IC=128 OC=64  waves 1x4 -> fp32 NCHW [64][6][6]
// ============================================================================
template <int HW, int IC, int OC, int NW_M, int NW_N, bool NCHW_OUT>
__global__ __launch_bounds__(256) void k_mconv(
    const __hip_bfloat16* __restrict__ in, const __hip_bfloat16* __restrict__ wt,
    const float* __restrict__ cb, const float* __restrict__ gg,
    const float* __restrict__ bbv, const float* __restrict__ bm,
    const float* __restrict__ bv, void* __restrict__ outp) {
  constexpr int HP = HW + 2;
  constexpr int MT = NW_M * 48;     // block M rows
  constexpr int ROWS = MT / HW;     // output h-rows per block (4)
  constexpr int TILES = HW / ROWS;  // blocks per image
  constexpr int WN = OC / NW_N;     // wave N width
  constexpr int NF = WN / 16;       // n-frags per wave
  constexpr int CP = HP;            // exact column count (26 / 14)
  constexpr int NCH = 6 * CP * 8;   // real 16B slots per window
  constexpr int NCHP = (NCH + 255) & ~255;
  constexpr int NLD = NCHP / 256;   // DMA chunks per thread (5 / 3)
  constexpr int NSTG = IC / 64;     // kc stages (4 / 2)
  constexpr int ABUF = NCHP * 16;   // bytes per window (20480 / 12288)
  constexpr int ICG = IC / 8;
  constexpr int EPITCH = OC + 1;
  constexpr int EBYTES = 48 * EPITCH * 4;
  constexpr int SMB = (2 * ABUF) > EBYTES ? (2 * ABUF) : EBYTES;

  __shared__ __align__(16) char smraw[SMB];
  float* se = (float*)smraw;  // epilogue tile (aliases windows, dead by then)

  const int tid = threadIdx.x;
  const int wv = tid >> 6, ln = tid & 63;
  const int wm = (NW_M == 2) ? (wv >> 1) : 0;
  const int wn = (NW_M == 2) ? (wv & 1) : wv;
  const int lhi = ln >> 4, llo = ln & 15;

  // XCD-aware remap (grid divisible by 8: CH is a multiple of 8):
  // consecutive blockIdx round-robin across XCDs; map so all TILES tiles of
  // one image land on the same XCD's L2.
  const int per = gridDim.x >> 3;
  const int xcd = blockIdx.x & 7, sl = blockIdx.x >> 3;
  const int b = xcd * (per / TILES) + sl / TILES;
  const int T = sl % TILES;
  const int h0 = T * ROWS;

  const __hip_bfloat16* inb = in + (size_t)b * HP * HP * IC;

  // staging source map: slot ci = tid + i*256 -> (r, c, kgslot), kg swizzled
  int srcoff[NLD];
#pragma unroll
  for (int i = 0; i < NLD; i++) {
    int ci = tid + i * 256;
    if (ci >= NCH) ci = NCH - 1;  // pad slots: dup read, dest lands in pad
    int kgslot = ci & 7;
    int rest = ci >> 3;
    int c = rest % CP;
    int r = rest / CP;
    int kg = kgslot ^ (c & 7);
    srcoff[i] = ((h0 + r) * HP + c) * IC + kg * 8;  // elements; +kc at use
  }
  // A-frag read precompute: spatial slot base & swizzle mask per (mt, pw)
  int spb[3][3], msk[3][3];
#pragma unroll
  for (int mt = 0; mt < 3; mt++) {
    int m = wm * 48 + mt * 16 + llo;
    int hl = m / HW, wl = m % HW;
#pragma unroll
    for (int pw = 0; pw < 3; pw++) {
      spb[mt][pw] = (hl * CP + wl + pw) * 8;
      msk[mt][pw] = (wl + pw) & 7;
    }
  }
  const __hip_bfloat16* wtb = wt + (size_t)(lhi * OC + wn * WN + llo) * 8;

  f32x4 acc[3][NF];
  const f32x4 fz = {0.f, 0.f, 0.f, 0.f};
#pragma unroll
  for (int i = 0; i < 3; i++)
#pragma unroll
    for (int j = 0; j < NF; j++) acc[i][j] = fz;

  // prologue: DMA stage 0 into window 0
#pragma unroll
  for (int i = 0; i < NLD; i++)
    gl2lds16(inb + srcoff[i], smraw + (tid + i * 256) * 16);
  __syncthreads();

#pragma unroll
  for (int s = 0; s < NSTG; s++) {
    if (s + 1 < NSTG) {  // prefetch next stage into other window
      char* nb = smraw + ((s + 1) & 1) * ABUF;
#pragma unroll
      for (int i = 0; i < NLD; i++)
        gl2lds16(inb + srcoff[i] + (s + 1) * 64, nb + (tid + i * 256) * 16);
    }
    const char* cw = smraw + (s & 1) * ABUF;
#pragma unroll
    for (int p = 0; p < 9; p++) {
      const int ph = p / 3, pw = p % 3;
#pragma unroll
      for (int ks = 0; ks < 2; ks++) {
        const int kg = ks * 4 + lhi;
        bf16x8 bf[NF];
#pragma unroll
        for (int j = 0; j < NF; j++)
          bf[j] = *(const bf16x8*)(wtb +
                                   ((size_t)(p * ICG + s * 8 + ks * 4) * OC) *
                                       8 +
                                   j * 128);
        bf16x8 af[3];
#pragma unroll
        for (int mt = 0; mt < 3; mt++) {
          int slot = spb[mt][pw] + ph * CP * 8 + (kg ^ msk[mt][pw]);
          af[mt] = *(const bf16x8*)(cw + slot * 16);
        }
#pragma unroll
        for (int mt = 0; mt < 3; mt++)
#pragma unroll
          for (int j = 0; j < NF; j++)
            acc[mt][j] = __builtin_amdgcn_mfma_f32_16x16x32_bf16(
                af[mt], bf[j], acc[mt][j], 0, 0, 0);
      }
    }
    __syncthreads();  // prefetch DMA drained; window s safe to overwrite
  }

  // ---- epilogue: per wm-pass: BN+ReLU -> E [48][EPITCH], 2x2 pool, store
  constexpr int PR = 48 / HW;  // h-rows per pass
  constexpr int POH = PR / 2;
  constexpr int OHW = HW / 2;
  constexpr int NP = POH * OHW * OC;
#pragma unroll
  for (int a = 0; a < NW_M; a++) {
    if (a) __syncthreads();
    if (wm == a) {
#pragma unroll
      for (int j = 0; j < NF; j++) {
        int n = wn * WN + j * 16 + llo;
        float scale = gg[n] * rsqrtf(bv[n] + EPS_BN);
        float bias = (cb[n] - bm[n]) * scale + bbv[n];
#pragma unroll
        for (int mt = 0; mt < 3; mt++)
#pragma unroll
          for (int r = 0; r < 4; r++) {
            int mrow = mt * 16 + lhi * 4 + r;
            se[mrow * EPITCH + n] = fmaxf(acc[mt][j][r] * scale + bias, 0.f);
          }
      }
    }
    __syncthreads();
    for (int s = tid; s < NP; s += 256) {
      int n = s % OC;
      int ow = (s / OC) % OHW;
      int ohl = s / (OC * OHW);
      int mloc = (2 * ohl) * HW + 2 * ow;
      float x0 = se[mloc * EPITCH + n];
      float x1 = se[(mloc + 1) * EPITCH + n];
      float x2 = se[(mloc + HW) * EPITCH + n];
      float x3 = se[(mloc + HW + 1) * EPITCH + n];
      float mx = fmaxf(fmaxf(x0, x1), fmaxf(x2, x3));
      int oh = (h0 >> 1) + a * POH + ohl;
      if (NCHW_OUT) {
        ((float*)outp)[(((size_t)b * OC + n) * OHW + oh) * OHW + ow] = mx;
      } else {  // padded bf16 NHWC [OHW+2][OHW+2][OC], interior at +1
        ((__hip_bfloat16*)
             outp)[(((size_t)b * (OHW + 2) + oh + 1) * (OHW + 2) + ow + 1) *
                       OC +
                   n] = __float2bfloat16(mx);
      }
    }
    if (a + 1 < NW_M) __syncthreads();
  }
}

// ============================================================================
// W_eff = W32 @ fc1_w, stored TRANSPOSED [2304][64] for coalesced reads.
// ============================================================================
__global__ void k_weff(const float* __restrict__ W32, const float* __restrict__ A1,
                       float* __restrict__ Wet) {
  int idx = blockIdx.x * 256 + threadIdx.x;  // 64*2304
  int r = idx / 2304, c = idx - r * 2304;
  float s = 0.f;
  for (int k = 0; k < 512; k++) s = fmaf(W32[r * 512 + k], A1[k * 2304 + c], s);
  Wet[c * 64 + r] = s;  // transposed store
}

// ============================================================================
// Fused q + spatial attention + fc3. 4 images per block (one wave each).
// q[b,n] = dot(out3[b,:], Wet[:,n]) + be[n]  (out3 NCHW fp32 [512][64][6][6]);
// scores = out3^T q; softmax(36); g = out3 @ attn; out = g @ fc3^T + b.
// ============================================================================
__global__ __launch_bounds__(256) void k_attn(
    const float* __restrict__ out3, const float* __restrict__ Wet,
    const float* __restrict__ be, const float* __restrict__ w3,
    const float* __restrict__ b3, float* __restrict__ out) {
  const int wv = threadIdx.x >> 6, t = threadIdx.x & 63;
  const int b = blockIdx.x * 4 + wv;
  __shared__ float ql[4][64], sc[4][36], gm[4][64];
  const float* o3 = out3 + (size_t)b * 2304;
  float qv = be[t];
  for (int k = 0; k < 2304; k++) qv = fmaf(o3[k], Wet[k * 64 + t], qv);
  ql[wv][t] = qv;
  __syncthreads();
  float s = -INFINITY;
  if (t < 36) {
    float acc = 0.f;
    for (int c = 0; c < 64; c++) acc = fmaf(o3[c * 36 + t], ql[wv][c], acc);
    s = acc;
  }
  float mx = s;
  for (int off = 32; off >= 1; off >>= 1) mx = fmaxf(mx, __shfl_xor(mx, off));
  float e = (t < 36) ? expf(s - mx) : 0.f;
  float sum = e;
  for (int off = 32; off >= 1; off >>= 1) sum += __shfl_xor(sum, off);
  if (t < 36) sc[wv][t] = e / sum;
  __syncthreads();
  float gv = 0.f;
  for (int hw = 0; hw < 36; hw++) gv = fmaf(o3[t * 36 + hw], sc[wv][hw], gv);
  gm[wv][t] = gv;
  __syncthreads();
  if (t < 7) {
    float acc = b3[t];
    for (int c = 0; c < 64; c++) acc = fmaf(w3[t * 64 + c], gm[wv][c], acc);
    out[b * 7 + t] = acc;
  }
}

// ============================================================================
extern "C" void kernel_launch(void* const* d_in, const int* in_sizes, int n_in,
                              void* d_out, int out_size, void* d_ws,
                              size_t ws_size, hipStream_t stream) {
  const float* x    = (const float*)d_in[0];
  const float* c1w  = (const float*)d_in[1];
  const float* c1b  = (const float*)d_in[2];
  const float* g1   = (const float*)d_in[3];
  const float* bb1  = (const float*)d_in[4];
  const float* m1   = (const float*)d_in[5];
  const float* v1   = (const float*)d_in[6];
  const float* c2w  = (const float*)d_in[7];
  const float* c2b  = (const float*)d_in[8];
  const float* g2   = (const float*)d_in[9];
  const float* bb2  = (const float*)d_in[10];
  const float* m2   = (const float*)d_in[11];
  const float* v2   = (const float*)d_in[12];
  const float* c3w  = (const float*)d_in[13];
  const float* c3b  = (const float*)d_in[14];
  const float* g3   = (const float*)d_in[15];
  const float* bb3  = (const float*)d_in[16];
  const float* m3   = (const float*)d_in[17];
  const float* v3   = (const float*)d_in[18];
  const float* fc1w = (const float*)d_in[19];
  const float* fc1b = (const float*)d_in[20];
  const float* fc2w = (const float*)d_in[21];
  const float* fc2b = (const float*)d_in[22];
  const float* attw = (const float*)d_in[23];
  const float* attb = (const float*)d_in[24];
  const float* fc3w = (const float*)d_in[25];
  const float* fc3b = (const float*)d_in[26];

  // chunking: per-chunk bf16 bufs out1p CH*173056 + out2p CH*25088 elems
  const size_t PER_CHUNK = (173056ULL + 25088ULL) * 2;  // bytes per image
  const size_t PERSIST = 4718592 + 589824 + 147456 + 131072 + 589824 + 256 +
                         8192;  // out3+wt2+wt3+W32+Wet+be+align
  int CH = 512;
  while (CH > 8 && (size_t)CH * PER_CHUNK + PERSIST > ws_size) CH >>= 1;
  const int NCHK = 512 / CH;

  char* base = (char*)d_ws;
  size_t off = 0;
  auto alloc = [&](size_t nbytes) -> void* {
    void* p = base + off;
    off = (off + nbytes + 255) & ~(size_t)255;
    return p;
  };
  __hip_bfloat16* out1p = (__hip_bfloat16*)alloc((size_t)CH * 173056 * 2);
  __hip_bfloat16* out2p = (__hip_bfloat16*)alloc((size_t)CH * 25088 * 2);
  float* out3          = (float*)alloc(4718592);
  __hip_bfloat16* wt2  = (__hip_bfloat16*)alloc(589824);
  __hip_bfloat16* wt3  = (__hip_bfloat16*)alloc(147456);
  float* W32           = (float*)alloc(131072);
  float* Wet           = (float*)alloc(589824);
  float* be            = (float*)alloc(256);

  // fused weight prep + FC collapse
  k_prep<<<1569, 256, 0, stream>>>(c2w, wt2, c3w, wt3, attw, fc2w, W32, fc1b,
                                   fc2b, attb, be);
  k_weff<<<576, 256, 0, stream>>>(W32, fc1w, Wet);

  for (int c = 0; c < NCHK; c++) {
    const float* xc = x + (size_t)c * CH * 2304;
    float* o3c = out3 + (size_t)c * CH * 2304;
    k_conv1<<<CH * 4, 256, 0, stream>>>(xc, c1w, c1b, g1, bb1, m1, v1, out1p,
                                        out2p);
    k_mconv<24, 256, 128, 2, 2, false>
        <<<CH * 6, 256, 0, stream>>>(out1p, wt2, c2b, g2, bb2, m2, v2, out2p);
    k_mconv<12, 128, 64, 1, 4, true>
        <<<CH * 3, 256, 0, stream>>>(out2p, wt3, c3b, g3, bb3, m3, v3, o3c);
  }

  k_attn<<<128, 256, 0, stream>>>(out3, Wet, be, fc3w, fc3b, (float*)d_out);
}

// Round 12
// 423.798 us; speedup vs baseline: 1.7130x; 1.1392x over previous
//
#include <hip/hip_runtime.h>
#include <hip/hip_bf16.h>
#include <math.h>

#define EPS_BN 1e-5f

typedef __bf16 bf16x8 __attribute__((ext_vector_type(8)));
typedef float f32x4 __attribute__((ext_vector_type(4)));
typedef float f32x2 __attribute__((ext_vector_type(2)));

// async global->LDS, 16B per lane. LDS dest must be wave-uniform base + lane*16
__device__ __forceinline__ void gl2lds16(const void* g, void* l) {
  __builtin_amdgcn_global_load_lds(
      (const __attribute__((address_space(1))) unsigned int*)g,
      (__attribute__((address_space(3))) unsigned int*)l, 16, 0, 0);
}

// ============================================================================
// conv1 + bias + BN + ReLU + maxpool2 (+ fused out2p halo zero + fused W_eff).
// blocks [0, n1):     conv1 band path: x[CH,1,48,48] fp32 ->
//                     out1p PADDED bf16 NHWC [CH][26][26][256] zero halo.
// blocks [n1, n1+576): W_eff = W32 @ fc1_w stored transposed [2304][64]
//                     (independent work fused to kill a launch; chunk 0 only).
// ============================================================================
__global__ __launch_bounds__(256) void k_conv1(
    const float* __restrict__ x, const float* __restrict__ w,
    const float* __restrict__ cb, const float* __restrict__ g,
    const float* __restrict__ bb, const float* __restrict__ m,
    const float* __restrict__ v, __hip_bfloat16* __restrict__ out1p,
    __hip_bfloat16* __restrict__ out2p, const float* __restrict__ W32,
    const float* __restrict__ fc1w, float* __restrict__ Wet, int n1) {
  __shared__ float xp[14 * 50];
  const int bq = blockIdx.x;
  const int t = threadIdx.x;
  if (bq >= n1) {  // ---- fused W_eff path ----
    int idx = (bq - n1) * 256 + t;  // 64*2304
    int r = idx / 2304, c = idx - r * 2304;
    float s = 0.f;
    for (int k = 0; k < 512; k++)
      s = fmaf(W32[r * 512 + k], fc1w[k * 2304 + c], s);
    Wet[c * 64 + r] = s;  // transposed store
    return;
  }
  const int b = bq >> 2, q = bq & 3;  // band q: output rows 6q..6q+5
  __hip_bfloat16* ob = out1p + (size_t)b * (26 * 26 * 256);
  const __hip_bfloat16 z = __float2bfloat16(0.f);
  // out1p halo zeroing split across bands
  if (q == 0)
    for (int i = t; i < 26 * 256; i += 256) ob[i] = z;
  if (q == 3)
    for (int i = t; i < 26 * 256; i += 256) ob[25 * 26 * 256 + i] = z;
  for (int i = t; i < 6 * 2 * 256; i += 256) {
    int r = 1 + 6 * q + (i >> 9), side = (i >> 8) & 1, c = i & 255;
    ob[(r * 26 + side * 25) * 256 + c] = z;
  }
  // fused out2p halo zeroing (quartered across bands)
  {
    __hip_bfloat16* o2 = out2p + (size_t)b * (14 * 14 * 128);
    if (q == 0)
      for (int i = t; i < 14 * 128; i += 256) o2[i] = z;
    if (q == 1)
      for (int i = t; i < 14 * 128; i += 256) o2[13 * 14 * 128 + i] = z;
    if (q == 2)
      for (int i = t; i < 6 * 2 * 128; i += 256) {
        int r = 1 + (i >> 8), side = (i >> 7) & 1, c = i & 127;
        o2[(r * 14 + side * 13) * 128 + c] = z;
      }
    if (q == 3)
      for (int i = t; i < 6 * 2 * 128; i += 256) {
        int r = 7 + (i >> 8), side = (i >> 7) & 1, c = i & 127;
        o2[(r * 14 + side * 13) * 128 + c] = z;
      }
  }
  for (int i = t; i < 14 * 50; i += 256) xp[i] = 0.f;
  __syncthreads();
  const float* xb = x + (size_t)b * 2304;
  for (int i = t; i < 14 * 48; i += 256) {
    int rr = i / 48, c = i - rr * 48;
    int gr = 12 * q - 1 + rr;
    if (gr >= 0 && gr < 48) xp[rr * 50 + c + 1] = xb[gr * 48 + c];
  }
  __syncthreads();
  float wr[9];
#pragma unroll
  for (int i = 0; i < 9; i++) wr[i] = w[t * 9 + i];
  const float scale = g[t] * rsqrtf(v[t] + EPS_BN);
  const float bias = (cb[t] - m[t]) * scale + bb[t];
#pragma unroll
  for (int ohl = 0; ohl < 6; ohl++) {
    const int r0 = 2 * ohl;
    f32x2 c01[4];
#pragma unroll
    for (int r = 0; r < 4; r++) c01[r] = *(const f32x2*)&xp[(r0 + r) * 50];
#pragma unroll 4
    for (int ow = 0; ow < 24; ow++) {
      f32x2 c23[4];
#pragma unroll
      for (int r = 0; r < 4; r++)
        c23[r] = *(const f32x2*)&xp[(r0 + r) * 50 + 2 * ow + 2];
      f32x2 s2a = 0.f, s2b = 0.f;  // dh = 0, 1 (packed over dw)
#pragma unroll
      for (int r = 0; r < 4; r++) {
        f32x2 p0 = c01[r], p2 = c23[r];
        f32x2 p1 = {p0.y, p2.x};
        if (r <= 2) {  // dh=0, kh=r
          s2a += p0 * wr[r * 3 + 0];
          s2a += p1 * wr[r * 3 + 1];
          s2a += p2 * wr[r * 3 + 2];
        }
        if (r >= 1) {  // dh=1, kh=r-1
          s2b += p0 * wr[(r - 1) * 3 + 0];
          s2b += p1 * wr[(r - 1) * 3 + 1];
          s2b += p2 * wr[(r - 1) * 3 + 2];
        }
      }
      f32x2 b0 = s2a * scale + bias;  // BN before pool
      f32x2 b1 = s2b * scale + bias;
      float mx = fmaxf(fmaxf(b0.x, b0.y), fmaxf(b1.x, b1.y));
      ob[((6 * q + ohl + 1) * 26 + (ow + 1)) * 256 + t] =
          __float2bfloat16(fmaxf(mx, 0.f));
#pragma unroll
      for (int r = 0; r < 4; r++) c01[r] = c23[r];
    }
  }
}

// ============================================================================
// Fused weight prep (one launch):
//   blocks [0,1152):    conv2 w -> bf16 [9][32][128][8]
//   blocks [1152,1440): conv3 w -> bf16 [9][16][64][8]
//   blocks [1440,1568): W32 = att_w[64,256] @ fc2_w[256,512]
//   block  1568:        b_eff = att_w@(fc2_w@fc1_b + fc2_b) + att_b
// ============================================================================
__global__ void k_prep(const float* __restrict__ c2w,
                       __hip_bfloat16* __restrict__ wt2,
                       const float* __restrict__ c3w,
                       __hip_bfloat16* __restrict__ wt3,
                       const float* __restrict__ attw,
                       const float* __restrict__ fc2w, float* __restrict__ W32,
                       const float* __restrict__ fc1b,
                       const float* __restrict__ fc2b,
                       const float* __restrict__ attb, float* __restrict__ be) {
  const int blk = blockIdx.x, tid = threadIdx.x;
  if (blk < 1152) {
    int idx = blk * 256 + tid;
    int icr = idx & 7;
    int oc = (idx >> 3) & 127;
    int rest = idx >> 10;
    int icg = rest & 31;
    int p = rest >> 5;
    wt2[idx] = __float2bfloat16(c2w[(oc * 256 + icg * 8 + icr) * 9 + p]);
  } else if (blk < 1440) {
    int idx = (blk - 1152) * 256 + tid;
    int icr = idx & 7;
    int oc = (idx >> 3) & 63;
    int rest = idx >> 9;
    int icg = rest & 15;
    int p = rest >> 4;
    wt3[idx] = __float2bfloat16(c3w[(oc * 128 + icg * 8 + icr) * 9 + p]);
  } else if (blk < 1568) {
    int idx = (blk - 1440) * 256 + tid;
    int r = idx >> 9, c = idx & 511;
    float s = 0.f;
    for (int k = 0; k < 256; k++)
      s = fmaf(attw[r * 256 + k], fc2w[k * 512 + c], s);
    W32[idx] = s;
  } else {
    __shared__ float t1[256];
    float s = fc2b[tid];
    for (int k = 0; k < 512; k++) s = fmaf(fc2w[tid * 512 + k], fc1b[k], s);
    t1[tid] = s;
    __syncthreads();
    if (tid < 64) {
      float r = attb[tid];
      for (int k = 0; k < 256; k++) r = fmaf(attw[tid * 256 + k], t1[k], r);
      be[tid] = r;
    }
  }
}

// ============================================================================
// conv2 MFMA implicit-GEMM (R6/R11 structure — best measured, 44% dense peak).
// ============================================================================
template <int HW, int IC, int OC, int NW_M, int NW_N>
__global__ __launch_bounds__(256) void k_mconv(
    const __hip_bfloat16* __restrict__ in, const __hip_bfloat16* __restrict__ wt,
    const float* __restrict__ cb, const float* __restrict__ gg,
    const float* __restrict__ bbv, const float* __restrict__ bm,
    const float* __restrict__ bv, __hip_bfloat16* __restrict__ outp) {
  constexpr int HP = HW + 2;
  constexpr int MT = NW_M * 48;
  constexpr int ROWS = MT / HW;
  constexpr int TILES = HW / ROWS;
  constexpr int WN = OC / NW_N;
  constexpr int NF = WN / 16;
  constexpr int CP = HP;
  constexpr int NCH = 6 * CP * 8;
  constexpr int NCHP = (NCH + 255) & ~255;
  constexpr int NLD = NCHP / 256;
  constexpr int NSTG = IC / 64;
  constexpr int ABUF = NCHP * 16;
  constexpr int ICG = IC / 8;
  constexpr int EPITCH = OC + 1;
  constexpr int EBYTES = 48 * EPITCH * 4;
  constexpr int SMB = (2 * ABUF) > EBYTES ? (2 * ABUF) : EBYTES;

  __shared__ __align__(16) char smraw[SMB];
  float* se = (float*)smraw;

  const int tid = threadIdx.x;
  const int wv = tid >> 6, ln = tid & 63;
  const int wm = wv >> 1, wn = wv & 1;
  const int lhi = ln >> 4, llo = ln & 15;

  // XCD-aware remap: all TILES tiles of an image on one XCD's L2.
  const int per = gridDim.x >> 3;
  const int xcd = blockIdx.x & 7, sl = blockIdx.x >> 3;
  const int b = xcd * (per / TILES) + sl / TILES;
  const int T = sl % TILES;
  const int h0 = T * ROWS;

  const __hip_bfloat16* inb = in + (size_t)b * HP * HP * IC;

  int srcoff[NLD];
#pragma unroll
  for (int i = 0; i < NLD; i++) {
    int ci = tid + i * 256;
    if (ci >= NCH) ci = NCH - 1;
    int kgslot = ci & 7;
    int rest = ci >> 3;
    int c = rest % CP;
    int r = rest / CP;
    int kg = kgslot ^ (c & 7);
    srcoff[i] = ((h0 + r) * HP + c) * IC + kg * 8;
  }
  int spb[3][3], msk[3][3];
#pragma unroll
  for (int mt = 0; mt < 3; mt++) {
    int m = wm * 48 + mt * 16 + llo;
    int hl = m / HW, wl = m % HW;
#pragma unroll
    for (int pw = 0; pw < 3; pw++) {
      spb[mt][pw] = (hl * CP + wl + pw) * 8;
      msk[mt][pw] = (wl + pw) & 7;
    }
  }
  const __hip_bfloat16* wtb = wt + (size_t)(lhi * OC + wn * WN + llo) * 8;

  f32x4 acc[3][NF];
  const f32x4 fz = {0.f, 0.f, 0.f, 0.f};
#pragma unroll
  for (int i = 0; i < 3; i++)
#pragma unroll
    for (int j = 0; j < NF; j++) acc[i][j] = fz;

#pragma unroll
  for (int i = 0; i < NLD; i++)
    gl2lds16(inb + srcoff[i], smraw + (tid + i * 256) * 16);
  __syncthreads();

#pragma unroll
  for (int s = 0; s < NSTG; s++) {
    if (s + 1 < NSTG) {
      char* nb = smraw + ((s + 1) & 1) * ABUF;
#pragma unroll
      for (int i = 0; i < NLD; i++)
        gl2lds16(inb + srcoff[i] + (s + 1) * 64, nb + (tid + i * 256) * 16);
    }
    const char* cw = smraw + (s & 1) * ABUF;
#pragma unroll
    for (int p = 0; p < 9; p++) {
      const int ph = p / 3, pw = p % 3;
#pragma unroll
      for (int ks = 0; ks < 2; ks++) {
        const int kg = ks * 4 + lhi;
        bf16x8 bf[NF];
#pragma unroll
        for (int j = 0; j < NF; j++)
          bf[j] = *(const bf16x8*)(wtb +
                                   ((size_t)(p * ICG + s * 8 + ks * 4) * OC) *
                                       8 +
                                   j * 128);
        bf16x8 af[3];
#pragma unroll
        for (int mt = 0; mt < 3; mt++) {
          int slot = spb[mt][pw] + ph * CP * 8 + (kg ^ msk[mt][pw]);
          af[mt] = *(const bf16x8*)(cw + slot * 16);
        }
#pragma unroll
        for (int mt = 0; mt < 3; mt++)
#pragma unroll
          for (int j = 0; j < NF; j++)
            acc[mt][j] = __builtin_amdgcn_mfma_f32_16x16x32_bf16(
                af[mt], bf[j], acc[mt][j], 0, 0, 0);
      }
    }
    __syncthreads();
  }

  constexpr int PR = 48 / HW;
  constexpr int POH = PR / 2;
  constexpr int OHW = HW / 2;
  constexpr int NP = POH * OHW * OC;
#pragma unroll
  for (int a = 0; a < NW_M; a++) {
    if (a) __syncthreads();
    if (wm == a) {
#pragma unroll
      for (int j = 0; j < NF; j++) {
        int n = wn * WN + j * 16 + llo;
        float scale = gg[n] * rsqrtf(bv[n] + EPS_BN);
        float bias = (cb[n] - bm[n]) * scale + bbv[n];
#pragma unroll
        for (int mt = 0; mt < 3; mt++)
#pragma unroll
          for (int r = 0; r < 4; r++) {
            int mrow = mt * 16 + lhi * 4 + r;
            se[mrow * EPITCH + n] = fmaxf(acc[mt][j][r] * scale + bias, 0.f);
          }
      }
    }
    __syncthreads();
    for (int s = tid; s < NP; s += 256) {
      int n = s % OC;
      int ow = (s / OC) % OHW;
      int ohl = s / (OC * OHW);
      int mloc = (2 * ohl) * HW + 2 * ow;
      float x0 = se[mloc * EPITCH + n];
      float x1 = se[(mloc + 1) * EPITCH + n];
      float x2 = se[(mloc + HW) * EPITCH + n];
      float x3 = se[(mloc + HW + 1) * EPITCH + n];
      float mx = fmaxf(fmaxf(x0, x1), fmaxf(x2, x3));
      int oh = (h0 >> 1) + a * POH + ohl;
      // padded bf16 NHWC [OHW+2][OHW+2][OC], interior at +1
      outp[(((size_t)b * (OHW + 2) + oh + 1) * (OHW + 2) + ow + 1) * OC + n] =
          __float2bfloat16(mx);
    }
    if (a + 1 < NW_M) __syncthreads();
  }
}

// ============================================================================
// FUSED conv3 + BN + ReLU + pool + spatial attention + fc3. One block/image.
// conv3: M=144 (whole 12x12 image), OC=64; 4 waves x 16 oc, MTW=9 m-frags.
// 9 MFMA per B-load (3x the B-reuse of the old conv3). out3 NEVER goes to
// global: pooled activations -> LDS act[64][37] (pitch 37: conflict-free).
// Phase B: q = act.Wet + be; softmax(36); g = act@attn; out = g@fc3^T + b3.
// LDS: dbuf windows 57344 + act 9472 + small -> ~68KB -> 2 blocks/CU (=grid).
// ============================================================================
__global__ __launch_bounds__(256) void k_c3attn(
    const __hip_bfloat16* __restrict__ in, const __hip_bfloat16* __restrict__ wt,
    const float* __restrict__ cb, const float* __restrict__ gg,
    const float* __restrict__ bbv, const float* __restrict__ bm,
    const float* __restrict__ bv, const float* __restrict__ Wet,
    const float* __restrict__ be, const float* __restrict__ w3,
    const float* __restrict__ b3, float* __restrict__ out, int b0) {
  constexpr int HW = 12, IC = 128, OC = 64, HP = 14, CP = 14;
  constexpr int NCH = 14 * CP * 8;          // 1568 16B slots per window
  constexpr int NCHP = (NCH + 255) & ~255;  // 1792
  constexpr int NLD = NCHP / 256;           // 7
  constexpr int NSTG = 2;
  constexpr int ABUF = NCHP * 16;  // 28672 B per window
  constexpr int ICG = 16;
  constexpr int EPITCH = OC + 1;  // 65

  __shared__ __align__(16) char smraw[2 * ABUF];  // se aliases this
  __shared__ float act[64 * 37];
  __shared__ float qp[4][64];
  __shared__ float ql[64], gm[64], sc[36];
  float* se = (float*)smraw;

  const int tid = threadIdx.x;
  const int wv = tid >> 6, ln = tid & 63;
  const int lhi = ln >> 4, llo = ln & 15;
  const int b = blockIdx.x;

  const __hip_bfloat16* inb = in + (size_t)b * HP * HP * IC;

  int srcoff[NLD];
#pragma unroll
  for (int i = 0; i < NLD; i++) {
    int ci = tid + i * 256;
    if (ci >= NCH) ci = NCH - 1;
    int kgslot = ci & 7;
    int rest = ci >> 3;
    int c = rest % CP;
    int r = rest / CP;
    int kg = kgslot ^ (c & 7);
    srcoff[i] = (r * HP + c) * IC + kg * 8;
  }
  int spb[9], wlv[9];
#pragma unroll
  for (int mt = 0; mt < 9; mt++) {
    int m = mt * 16 + llo;
    int hl = m / HW, wl = m % HW;
    spb[mt] = (hl * CP + wl) * 8;
    wlv[mt] = wl;
  }
  const __hip_bfloat16* wtb = wt + (size_t)(lhi * OC + wv * 16 + llo) * 8;

  f32x4 acc[9];
  const f32x4 fz = {0.f, 0.f, 0.f, 0.f};
#pragma unroll
  for (int i = 0; i < 9; i++) acc[i] = fz;

#pragma unroll
  for (int i = 0; i < NLD; i++)
    gl2lds16(inb + srcoff[i], smraw + (tid + i * 256) * 16);
  __syncthreads();

#pragma unroll
  for (int s = 0; s < NSTG; s++) {
    if (s + 1 < NSTG) {
      char* nb = smraw + ((s + 1) & 1) * ABUF;
#pragma unroll
      for (int i = 0; i < NLD; i++)
        gl2lds16(inb + srcoff[i] + (s + 1) * 64, nb + (tid + i * 256) * 16);
    }
    const char* cw = smraw + (s & 1) * ABUF;
#pragma unroll
    for (int tt = 0; tt < 18; tt++) {
      const int p = tt >> 1, ks = tt & 1;
      const int ph = p / 3, pw = p % 3;
      const int kg = ks * 4 + lhi;
      bf16x8 bf =
          *(const bf16x8*)(wtb + ((size_t)(p * ICG + s * 8 + ks * 4) * OC) * 8);
#pragma unroll
      for (int mt = 0; mt < 9; mt++) {
        int slot = spb[mt] + (ph * CP + pw) * 8 + (kg ^ ((wlv[mt] + pw) & 7));
        bf16x8 af = *(const bf16x8*)(cw + slot * 16);
        acc[mt] = __builtin_amdgcn_mfma_f32_16x16x32_bf16(af, bf, acc[mt], 0,
                                                          0, 0);
      }
    }
    __syncthreads();
  }

  // ---- epilogue: 3 passes of 48 rows -> se [48][65]; pool -> act LDS
  {
    const int n = wv * 16 + llo;
    const float scale = gg[n] * rsqrtf(bv[n] + EPS_BN);
    const float bias = (cb[n] - bm[n]) * scale + bbv[n];
#pragma unroll
    for (int pz = 0; pz < 3; pz++) {
      if (pz) __syncthreads();
#pragma unroll
      for (int mtl = 0; mtl < 3; mtl++)
#pragma unroll
        for (int r = 0; r < 4; r++) {
          int mrow = mtl * 16 + lhi * 4 + r;
          se[mrow * EPITCH + n] =
              fmaxf(acc[pz * 3 + mtl][r] * scale + bias, 0.f);
        }
      __syncthreads();
      for (int sI = tid; sI < 2 * 6 * 64; sI += 256) {
        int nn = sI % 64;
        int ow = (sI / 64) % 6;
        int ohl = sI / (64 * 6);
        int mloc = (2 * ohl) * HW + 2 * ow;
        float x0 = se[mloc * EPITCH + nn];
        float x1 = se[(mloc + 1) * EPITCH + nn];
        float x2 = se[(mloc + HW) * EPITCH + nn];
        float x3 = se[(mloc + HW + 1) * EPITCH + nn];
        float mx = fmaxf(fmaxf(x0, x1), fmaxf(x2, x3));
        act[nn * 37 + (pz * 2 + ohl) * 6 + ow] = mx;
      }
    }
  }
  __syncthreads();

  // ---- phase B: q (wave-split over k), softmax, g, fc3
  {
    float qpv = 0.f;
    const int n = ln;
#pragma unroll 2
    for (int c2 = wv * 16; c2 < wv * 16 + 16; c2++)
      for (int hw = 0; hw < 36; hw++)
        qpv = fmaf(act[c2 * 37 + hw], Wet[(c2 * 36 + hw) * 64 + n], qpv);
    qp[wv][n] = qpv;
  }
  __syncthreads();
  if (tid < 64)
    ql[tid] = be[tid] + qp[0][tid] + qp[1][tid] + qp[2][tid] + qp[3][tid];
  __syncthreads();
  if (wv == 0) {
    float s = -INFINITY;
    if (ln < 36) {
      float a = 0.f;
      for (int c = 0; c < 64; c++) a = fmaf(act[c * 37 + ln], ql[c], a);
      s = a;
    }
    float mx = s;
    for (int off = 32; off >= 1; off >>= 1)
      mx = fmaxf(mx, __shfl_xor(mx, off));
    float e = (ln < 36) ? expf(s - mx) : 0.f;
    float sum = e;
    for (int off = 32; off >= 1; off >>= 1) sum += __shfl_xor(sum, off);
    if (ln < 36) sc[ln] = e / sum;
  }
  __syncthreads();
  if (wv == 0) {
    float gv = 0.f;
    for (int hw = 0; hw < 36; hw++) gv = fmaf(act[ln * 37 + hw], sc[hw], gv);
    gm[ln] = gv;
  }
  __syncthreads();
  if (tid < 7) {
    float a = b3[tid];
    for (int c = 0; c < 64; c++) a = fmaf(w3[tid * 64 + c], gm[c], a);
    out[(size_t)(b0 + b) * 7 + tid] = a;
  }
}

// ============================================================================
extern "C" void kernel_launch(void* const* d_in, const int* in_sizes, int n_in,
                              void* d_out, int out_size, void* d_ws,
                              size_t ws_size, hipStream_t stream) {
  const float* x    = (const float*)d_in[0];
  const float* c1w  = (const float*)d_in[1];
  const float* c1b  = (const float*)d_in[2];
  const float* g1   = (const float*)d_in[3];
  const float* bb1  = (const float*)d_in[4];
  const float* m1   = (const float*)d_in[5];
  const float* v1   = (const float*)d_in[6];
  const float* c2w  = (const float*)d_in[7];
  const float* c2b  = (const float*)d_in[8];
  const float* g2   = (const float*)d_in[9];
  const float* bb2  = (const float*)d_in[10];
  const float* m2   = (const float*)d_in[11];
  const float* v2   = (const float*)d_in[12];
  const float* c3w  = (const float*)d_in[13];
  const float* c3b  = (const float*)d_in[14];
  const float* g3   = (const float*)d_in[15];
  const float* bb3  = (const float*)d_in[16];
  const float* m3   = (const float*)d_in[17];
  const float* v3   = (const float*)d_in[18];
  const float* fc1w = (const float*)d_in[19];
  const float* fc1b = (const float*)d_in[20];
  const float* fc2w = (const float*)d_in[21];
  const float* fc2b = (const float*)d_in[22];
  const float* attw = (const float*)d_in[23];
  const float* attb = (const float*)d_in[24];
  const float* fc3w = (const float*)d_in[25];
  const float* fc3b = (const float*)d_in[26];

  const size_t PER_CHUNK = (173056ULL + 25088ULL) * 2;  // bytes per image
  const size_t PERSIST = 589824 + 147456 + 131072 + 589824 + 256 + 8192;
  int CH = 512;
  while (CH > 8 && (size_t)CH * PER_CHUNK + PERSIST > ws_size) CH >>= 1;
  const int NCHK = 512 / CH;

  char* base = (char*)d_ws;
  size_t off = 0;
  auto alloc = [&](size_t nbytes) -> void* {
    void* p = base + off;
    off = (off + nbytes + 255) & ~(size_t)255;
    return p;
  };
  __hip_bfloat16* out1p = (__hip_bfloat16*)alloc((size_t)CH * 173056 * 2);
  __hip_bfloat16* out2p = (__hip_bfloat16*)alloc((size_t)CH * 25088 * 2);
  __hip_bfloat16* wt2  = (__hip_bfloat16*)alloc(589824);
  __hip_bfloat16* wt3  = (__hip_bfloat16*)alloc(147456);
  float* W32           = (float*)alloc(131072);
  float* Wet           = (float*)alloc(589824);
  float* be            = (float*)alloc(256);

  k_prep<<<1569, 256, 0, stream>>>(c2w, wt2, c3w, wt3, attw, fc2w, W32, fc1b,
                                   fc2b, attb, be);

  for (int c = 0; c < NCHK; c++) {
    const float* xc = x + (size_t)c * CH * 2304;
    const int n1 = CH * 4;
    const int grid1 = n1 + (c == 0 ? 576 : 0);  // W_eff fused in chunk 0
    k_conv1<<<grid1, 256, 0, stream>>>(xc, c1w, c1b, g1, bb1, m1, v1, out1p,
                                       out2p, W32, fc1w, Wet, n1);
    k_mconv<24, 256, 128, 2, 2>
        <<<CH * 6, 256, 0, stream>>>(out1p, wt2, c2b, g2, bb2, m2, v2, out2p);
    k_c3attn<<<CH, 256, 0, stream>>>(out2p, wt3, c3b, g3, bb3, m3, v3, Wet, be,
                                     fc3w, fc3b, (float*)d_out, c * CH);
  }
}

// Round 13
// 419.882 us; speedup vs baseline: 1.7290x; 1.0093x over previous
//
#include <hip/hip_runtime.h>
#include <hip/hip_bf16.h>
#include <math.h>

#define EPS_BN 1e-5f

typedef __bf16 bf16x8 __attribute__((ext_vector_type(8)));
typedef float f32x4 __attribute__((ext_vector_type(4)));
typedef float f32x2 __attribute__((ext_vector_type(2)));

// async global->LDS, 16B per lane. LDS dest must be wave-uniform base + lane*16
__device__ __forceinline__ void gl2lds16(const void* g, void* l) {
  __builtin_amdgcn_global_load_lds(
      (const __attribute__((address_space(1))) unsigned int*)g,
      (__attribute__((address_space(3))) unsigned int*)l, 16, 0, 0);
}

// ============================================================================
// conv1 + bias + BN + ReLU + maxpool2 (+ fused out2p halo zero + fused W_eff).
// blocks [0, n1):      conv1 band path -> out1p padded bf16 NHWC [26][26][256]
// blocks [n1, n1+576): W_eff = W32 @ fc1_w stored transposed [2304][64]
// ============================================================================
__global__ __launch_bounds__(256) void k_conv1(
    const float* __restrict__ x, const float* __restrict__ w,
    const float* __restrict__ cb, const float* __restrict__ g,
    const float* __restrict__ bb, const float* __restrict__ m,
    const float* __restrict__ v, __hip_bfloat16* __restrict__ out1p,
    __hip_bfloat16* __restrict__ out2p, const float* __restrict__ W32,
    const float* __restrict__ fc1w, float* __restrict__ Wet, int n1) {
  __shared__ float xp[14 * 50];
  const int bq = blockIdx.x;
  const int t = threadIdx.x;
  if (bq >= n1) {  // ---- fused W_eff path ----
    int idx = (bq - n1) * 256 + t;  // 64*2304
    int r = idx / 2304, c = idx - r * 2304;
    float s = 0.f;
    for (int k = 0; k < 512; k++)
      s = fmaf(W32[r * 512 + k], fc1w[k * 2304 + c], s);
    Wet[c * 64 + r] = s;  // transposed store
    return;
  }
  const int b = bq >> 2, q = bq & 3;  // band q: output rows 6q..6q+5
  __hip_bfloat16* ob = out1p + (size_t)b * (26 * 26 * 256);
  const __hip_bfloat16 z = __float2bfloat16(0.f);
  if (q == 0)
    for (int i = t; i < 26 * 256; i += 256) ob[i] = z;
  if (q == 3)
    for (int i = t; i < 26 * 256; i += 256) ob[25 * 26 * 256 + i] = z;
  for (int i = t; i < 6 * 2 * 256; i += 256) {
    int r = 1 + 6 * q + (i >> 9), side = (i >> 8) & 1, c = i & 255;
    ob[(r * 26 + side * 25) * 256 + c] = z;
  }
  {
    __hip_bfloat16* o2 = out2p + (size_t)b * (14 * 14 * 128);
    if (q == 0)
      for (int i = t; i < 14 * 128; i += 256) o2[i] = z;
    if (q == 1)
      for (int i = t; i < 14 * 128; i += 256) o2[13 * 14 * 128 + i] = z;
    if (q == 2)
      for (int i = t; i < 6 * 2 * 128; i += 256) {
        int r = 1 + (i >> 8), side = (i >> 7) & 1, c = i & 127;
        o2[(r * 14 + side * 13) * 128 + c] = z;
      }
    if (q == 3)
      for (int i = t; i < 6 * 2 * 128; i += 256) {
        int r = 7 + (i >> 8), side = (i >> 7) & 1, c = i & 127;
        o2[(r * 14 + side * 13) * 128 + c] = z;
      }
  }
  for (int i = t; i < 14 * 50; i += 256) xp[i] = 0.f;
  __syncthreads();
  const float* xb = x + (size_t)b * 2304;
  for (int i = t; i < 14 * 48; i += 256) {
    int rr = i / 48, c = i - rr * 48;
    int gr = 12 * q - 1 + rr;
    if (gr >= 0 && gr < 48) xp[rr * 50 + c + 1] = xb[gr * 48 + c];
  }
  __syncthreads();
  float wr[9];
#pragma unroll
  for (int i = 0; i < 9; i++) wr[i] = w[t * 9 + i];
  const float scale = g[t] * rsqrtf(v[t] + EPS_BN);
  const float bias = (cb[t] - m[t]) * scale + bb[t];
#pragma unroll
  for (int ohl = 0; ohl < 6; ohl++) {
    const int r0 = 2 * ohl;
    f32x2 c01[4];
#pragma unroll
    for (int r = 0; r < 4; r++) c01[r] = *(const f32x2*)&xp[(r0 + r) * 50];
#pragma unroll 4
    for (int ow = 0; ow < 24; ow++) {
      f32x2 c23[4];
#pragma unroll
      for (int r = 0; r < 4; r++)
        c23[r] = *(const f32x2*)&xp[(r0 + r) * 50 + 2 * ow + 2];
      f32x2 s2a = 0.f, s2b = 0.f;  // dh = 0, 1 (packed over dw)
#pragma unroll
      for (int r = 0; r < 4; r++) {
        f32x2 p0 = c01[r], p2 = c23[r];
        f32x2 p1 = {p0.y, p2.x};
        if (r <= 2) {
          s2a += p0 * wr[r * 3 + 0];
          s2a += p1 * wr[r * 3 + 1];
          s2a += p2 * wr[r * 3 + 2];
        }
        if (r >= 1) {
          s2b += p0 * wr[(r - 1) * 3 + 0];
          s2b += p1 * wr[(r - 1) * 3 + 1];
          s2b += p2 * wr[(r - 1) * 3 + 2];
        }
      }
      f32x2 b0 = s2a * scale + bias;  // BN before pool
      f32x2 b1 = s2b * scale + bias;
      float mx = fmaxf(fmaxf(b0.x, b0.y), fmaxf(b1.x, b1.y));
      ob[((6 * q + ohl + 1) * 26 + (ow + 1)) * 256 + t] =
          __float2bfloat16(fmaxf(mx, 0.f));
#pragma unroll
      for (int r = 0; r < 4; r++) c01[r] = c23[r];
    }
  }
}

// ============================================================================
// Fused weight prep (one launch):
//   blocks [0,1152):    conv2 w -> bf16 [9][8][128][4][8] (wave-contiguous:
//                       one wave B-load = 64 lanes x 16B = 1KB segment)
//   blocks [1152,1440): conv3 w -> bf16 [9][16][64][8]
//   blocks [1440,1568): W32 = att_w[64,256] @ fc2_w[256,512]
//   block  1568:        b_eff = att_w@(fc2_w@fc1_b + fc2_b) + att_b
// ============================================================================
__global__ void k_prep(const float* __restrict__ c2w,
                       __hip_bfloat16* __restrict__ wt2,
                       const float* __restrict__ c3w,
                       __hip_bfloat16* __restrict__ wt3,
                       const float* __restrict__ attw,
                       const float* __restrict__ fc2w, float* __restrict__ W32,
                       const float* __restrict__ fc1b,
                       const float* __restrict__ fc2b,
                       const float* __restrict__ attb, float* __restrict__ be) {
  const int blk = blockIdx.x, tid = threadIdx.x;
  if (blk < 1152) {  // conv2 wt: [9][8][128][4][8]
    int idx = blk * 256 + tid;
    int icr = idx & 7;
    int lhi = (idx >> 3) & 3;
    int oc = (idx >> 5) & 127;
    int rest = idx >> 12;
    int kb = rest & 7;
    int p = rest >> 3;
    int ic = kb * 32 + lhi * 8 + icr;
    wt2[idx] = __float2bfloat16(c2w[(oc * 256 + ic) * 9 + p]);
  } else if (blk < 1440) {  // conv3 wt: [9][16][64][8]
    int idx = (blk - 1152) * 256 + tid;
    int icr = idx & 7;
    int oc = (idx >> 3) & 63;
    int rest = idx >> 9;
    int icg = rest & 15;
    int p = rest >> 4;
    wt3[idx] = __float2bfloat16(c3w[(oc * 128 + icg * 8 + icr) * 9 + p]);
  } else if (blk < 1568) {
    int idx = (blk - 1440) * 256 + tid;
    int r = idx >> 9, c = idx & 511;
    float s = 0.f;
    for (int k = 0; k < 256; k++)
      s = fmaf(attw[r * 256 + k], fc2w[k * 512 + c], s);
    W32[idx] = s;
  } else {
    __shared__ float t1[256];
    float s = fc2b[tid];
    for (int k = 0; k < 512; k++) s = fmaf(fc2w[tid * 512 + k], fc1b[k], s);
    t1[tid] = s;
    __syncthreads();
    if (tid < 64) {
      float r = attb[tid];
      for (int k = 0; k < 256; k++) r = fmaf(attw[tid * 256 + k], t1[k], r);
      be[tid] = r;
    }
  }
}

// ============================================================================
// conv2 MFMA implicit-GEMM + BN + ReLU + pool (bf16, fp32 acc).
// in: padded bf16 NHWC [26][26][256]; wt: [9][8][128][4][8].
// 4 waves SHARE M = 96 rows (half the B-per-MFMA of the 2x2 split); each wave
// owns 32 oc (NF=2). K-loop = 72 unrolled steps with a DEPTH-3 register ring
// on B (D=3 not 4: ring = 24 VGPRs keeps total <= 170 -> 3 waves/SIMD;
// R9's D=4 landed at 172 regs = 2/SIMD and erased the ring's duty gain).
// Next-window DMA issued LATE (step 13, after that step's refill): in-stage
// B consumes never drain the DMA chain in the ordered vmcnt queue.
// A window (6 rows x 26 cols x 64ic, 20KB) dbuf in LDS via global_load_lds;
// xor-swizzled slots keep fragment reads <=2-way bank aliased (free).
// XCD swizzle: all 6 tiles of an image on one XCD's L2 (R11: FETCH -27%).
// ============================================================================
__global__ __launch_bounds__(256) void k_mconv2(
    const __hip_bfloat16* __restrict__ in, const __hip_bfloat16* __restrict__ wt,
    const float* __restrict__ cb, const float* __restrict__ gg,
    const float* __restrict__ bbv, const float* __restrict__ bm,
    const float* __restrict__ bv, __hip_bfloat16* __restrict__ outp) {
  constexpr int HW = 24, IC = 256, OC = 128, HP = 26, CP = 26;
  constexpr int MTW = 6;            // m-frags per wave (all waves share M=96)
  constexpr int ROWS = 4;           // output h-rows per block
  constexpr int TILES = 6;          // blocks per image
  constexpr int WN = 32;            // wave N width
  constexpr int NF = 2;             // n-frags per wave
  constexpr int NCH = 6 * CP * 8;   // 1248 16B slots per window
  constexpr int NCHP = (NCH + 255) & ~255;  // 1280
  constexpr int NLD = NCHP / 256;   // 5
  constexpr int NSTG = 4;           // kc stages
  constexpr int ABUF = NCHP * 16;   // 20480 B per window
  constexpr int KG = IC / 32;       // 8
  constexpr int EPITCH = OC + 1;
  constexpr int EBYTES = 48 * EPITCH * 4;
  constexpr int SMB = (2 * ABUF) > EBYTES ? (2 * ABUF) : EBYTES;
  constexpr int NSTEP = NSTG * 18;  // 72
  constexpr int D = 3;              // B prefetch depth (register ring)

  __shared__ __align__(16) char smraw[SMB];
  float* se = (float*)smraw;

  const int tid = threadIdx.x;
  const int wn = tid >> 6, ln = tid & 63;
  const int lhi = ln >> 4, llo = ln & 15;

  // XCD-aware remap: all TILES tiles of an image on one XCD's L2.
  const int per = gridDim.x >> 3;
  const int xcd = blockIdx.x & 7, sl = blockIdx.x >> 3;
  const int b = xcd * (per / TILES) + sl / TILES;
  const int T = sl % TILES;
  const int h0 = T * ROWS;

  const __hip_bfloat16* inb = in + (size_t)b * HP * HP * IC;

  int srcoff[NLD];
#pragma unroll
  for (int i = 0; i < NLD; i++) {
    int ci = tid + i * 256;
    if (ci >= NCH) ci = NCH - 1;
    int kgslot = ci & 7;
    int rest = ci >> 3;
    int c = rest % CP;
    int r = rest / CP;
    int kg = kgslot ^ (c & 7);
    srcoff[i] = ((h0 + r) * HP + c) * IC + kg * 8;
  }
  int spb[MTW], wlv[MTW];
#pragma unroll
  for (int mt = 0; mt < MTW; mt++) {
    int m = mt * 16 + llo;
    int hl = m / HW, wl = m % HW;
    spb[mt] = (hl * CP + wl) * 8;
    wlv[mt] = wl;
  }
  const __hip_bfloat16* wtb = wt + (wn * WN + llo) * 32 + lhi * 8;

  f32x4 acc[MTW][NF];
  const f32x4 fz = {0.f, 0.f, 0.f, 0.f};
#pragma unroll
  for (int i = 0; i < MTW; i++)
#pragma unroll
    for (int j = 0; j < NF; j++) acc[i][j] = fz;

  // prologue: DMA stage 0 into window 0; preload B ring for steps 0..D-1
#pragma unroll
  for (int i = 0; i < NLD; i++)
    gl2lds16(inb + srcoff[i], smraw + (tid + i * 256) * 16);
  bf16x8 bq[D][NF];
#pragma unroll
  for (int d = 0; d < D; d++) {
    const int sg = d / 18, pg = (d % 18) >> 1, kf = d & 1;
#pragma unroll
    for (int j = 0; j < NF; j++)
      bq[d][j] = *(const bf16x8*)(wtb +
                                  (size_t)((pg * KG + sg * 2 + kf) * OC) * 32 +
                                  j * 512);
  }
  __syncthreads();

#pragma unroll
  for (int s = 0; s < NSTG; s++) {
    const char* cw = smraw + (s & 1) * ABUF;
#pragma unroll
    for (int t = 0; t < 18; t++) {
      const int g = s * 18 + t;
      const int p = t >> 1, ks = t & 1;
      const int ph = p / 3, pw = p % 3;
      const int kg = ks * 4 + lhi;
      // consume bq[g%D]
#pragma unroll
      for (int mt = 0; mt < MTW; mt++) {
        int slot = spb[mt] + (ph * CP + pw) * 8 + (kg ^ ((wlv[mt] + pw) & 7));
        bf16x8 af = *(const bf16x8*)(cw + slot * 16);
#pragma unroll
        for (int j = 0; j < NF; j++)
          acc[mt][j] = __builtin_amdgcn_mfma_f32_16x16x32_bf16(
              af, bq[g % D][j], acc[mt][j], 0, 0, 0);
      }
      // refill ring slot for step g+D
      if (g + D < NSTEP) {
        const int gf = g + D;
        const int sg = gf / 18, pg = (gf % 18) >> 1, kf = gf & 1;
#pragma unroll
        for (int j = 0; j < NF; j++)
          bq[gf % D][j] =
              *(const bf16x8*)(wtb +
                               (size_t)((pg * KG + sg * 2 + kf) * OC) * 32 +
                               j * 512);
      }
      // issue next-window DMA LATE (after this step's ring refill)
      if (t == 13 && s + 1 < NSTG) {
        char* nb = smraw + ((s + 1) & 1) * ABUF;
#pragma unroll
        for (int i = 0; i < NLD; i++)
          gl2lds16(inb + srcoff[i] + (s + 1) * 64, nb + (tid + i * 256) * 16);
      }
    }
    __syncthreads();  // window s reads done; DMA for s+1 drained
  }

  // ---- epilogue in 48-row passes: BN+ReLU -> se [48][129], pool, store
  constexpr int OHW = HW / 2;
  constexpr int NP = 1 * OHW * OC;  // pooled rows per pass = 1
#pragma unroll
  for (int pz = 0; pz < 2; pz++) {
    if (pz) __syncthreads();
#pragma unroll
    for (int j = 0; j < NF; j++) {
      int n = wn * WN + j * 16 + llo;
      float scale = gg[n] * rsqrtf(bv[n] + EPS_BN);
      float bias = (cb[n] - bm[n]) * scale + bbv[n];
#pragma unroll
      for (int mtl = 0; mtl < 3; mtl++)
#pragma unroll
        for (int r = 0; r < 4; r++) {
          int mrow = mtl * 16 + lhi * 4 + r;
          se[mrow * EPITCH + n] =
              fmaxf(acc[pz * 3 + mtl][j][r] * scale + bias, 0.f);
        }
    }
    __syncthreads();
    for (int sI = tid; sI < NP; sI += 256) {
      int n = sI % OC;
      int ow = (sI / OC) % OHW;
      int mloc = 2 * ow;
      float x0 = se[mloc * EPITCH + n];
      float x1 = se[(mloc + 1) * EPITCH + n];
      float x2 = se[(mloc + HW) * EPITCH + n];
      float x3 = se[(mloc + HW + 1) * EPITCH + n];
      float mx = fmaxf(fmaxf(x0, x1), fmaxf(x2, x3));
      int oh = (h0 >> 1) + pz;
      // padded bf16 NHWC [14][14][128], interior at +1
      outp[(((size_t)b * 14 + oh + 1) * 14 + ow + 1) * OC + n] =
          __float2bfloat16(mx);
    }
  }
}

// ============================================================================
// FUSED conv3 + BN + ReLU + pool + spatial attention + fc3. One block/image.
// (unchanged from R12 — measured good)
// ============================================================================
__global__ __launch_bounds__(256) void k_c3attn(
    const __hip_bfloat16* __restrict__ in, const __hip_bfloat16* __restrict__ wt,
    const float* __restrict__ cb, const float* __restrict__ gg,
    const float* __restrict__ bbv, const float* __restrict__ bm,
    const float* __restrict__ bv, const float* __restrict__ Wet,
    const float* __restrict__ be, const float* __restrict__ w3,
    const float* __restrict__ b3, float* __restrict__ out, int b0) {
  constexpr int HW = 12, IC = 128, OC = 64, HP = 14, CP = 14;
  constexpr int NCH = 14 * CP * 8;
  constexpr int NCHP = (NCH + 255) & ~255;
  constexpr int NLD = NCHP / 256;
  constexpr int NSTG = 2;
  constexpr int ABUF = NCHP * 16;
  constexpr int ICG = 16;
  constexpr int EPITCH = OC + 1;

  __shared__ __align__(16) char smraw[2 * ABUF];
  __shared__ float act[64 * 37];
  __shared__ float qp[4][64];
  __shared__ float ql[64], gm[64], sc[36];
  float* se = (float*)smraw;

  const int tid = threadIdx.x;
  const int wv = tid >> 6, ln = tid & 63;
  const int lhi = ln >> 4, llo = ln & 15;
  const int b = blockIdx.x;

  const __hip_bfloat16* inb = in + (size_t)b * HP * HP * IC;

  int srcoff[NLD];
#pragma unroll
  for (int i = 0; i < NLD; i++) {
    int ci = tid + i * 256;
    if (ci >= NCH) ci = NCH - 1;
    int kgslot = ci & 7;
    int rest = ci >> 3;
    int c = rest % CP;
    int r = rest / CP;
    int kg = kgslot ^ (c & 7);
    srcoff[i] = (r * HP + c) * IC + kg * 8;
  }
  int spb[9], wlv[9];
#pragma unroll
  for (int mt = 0; mt < 9; mt++) {
    int m = mt * 16 + llo;
    int hl = m / HW, wl = m % HW;
    spb[mt] = (hl * CP + wl) * 8;
    wlv[mt] = wl;
  }
  const __hip_bfloat16* wtb = wt + (size_t)(lhi * OC + wv * 16 + llo) * 8;

  f32x4 acc[9];
  const f32x4 fz = {0.f, 0.f, 0.f, 0.f};
#pragma unroll
  for (int i = 0; i < 9; i++) acc[i] = fz;

#pragma unroll
  for (int i = 0; i < NLD; i++)
    gl2lds16(inb + srcoff[i], smraw + (tid + i * 256) * 16);
  __syncthreads();

#pragma unroll
  for (int s = 0; s < NSTG; s++) {
    if (s + 1 < NSTG) {
      char* nb = smraw + ((s + 1) & 1) * ABUF;
#pragma unroll
      for (int i = 0; i < NLD; i++)
        gl2lds16(inb + srcoff[i] + (s + 1) * 64, nb + (tid + i * 256) * 16);
    }
    const char* cw = smraw + (s & 1) * ABUF;
#pragma unroll
    for (int tt = 0; tt < 18; tt++) {
      const int p = tt >> 1, ks = tt & 1;
      const int ph = p / 3, pw = p % 3;
      const int kg = ks * 4 + lhi;
      bf16x8 bf =
          *(const bf16x8*)(wtb + ((size_t)(p * ICG + s * 8 + ks * 4) * OC) * 8);
#pragma unroll
      for (int mt = 0; mt < 9; mt++) {
        int slot = spb[mt] + (ph * CP + pw) * 8 + (kg ^ ((wlv[mt] + pw) & 7));
        bf16x8 af = *(const bf16x8*)(cw + slot * 16);
        acc[mt] = __builtin_amdgcn_mfma_f32_16x16x32_bf16(af, bf, acc[mt], 0,
                                                          0, 0);
      }
    }
    __syncthreads();
  }

  {
    const int n = wv * 16 + llo;
    const float scale = gg[n] * rsqrtf(bv[n] + EPS_BN);
    const float bias = (cb[n] - bm[n]) * scale + bbv[n];
#pragma unroll
    for (int pz = 0; pz < 3; pz++) {
      if (pz) __syncthreads();
#pragma unroll
      for (int mtl = 0; mtl < 3; mtl++)
#pragma unroll
        for (int r = 0; r < 4; r++) {
          int mrow = mtl * 16 + lhi * 4 + r;
          se[mrow * EPITCH + n] =
              fmaxf(acc[pz * 3 + mtl][r] * scale + bias, 0.f);
        }
      __syncthreads();
      for (int sI = tid; sI < 2 * 6 * 64; sI += 256) {
        int nn = sI % 64;
        int ow = (sI / 64) % 6;
        int ohl = sI / (64 * 6);
        int mloc = (2 * ohl) * HW + 2 * ow;
        float x0 = se[mloc * EPITCH + nn];
        float x1 = se[(mloc + 1) * EPITCH + nn];
        float x2 = se[(mloc + HW) * EPITCH + nn];
        float x3 = se[(mloc + HW + 1) * EPITCH + nn];
        float mx = fmaxf(fmaxf(x0, x1), fmaxf(x2, x3));
        act[nn * 37 + (pz * 2 + ohl) * 6 + ow] = mx;
      }
    }
  }
  __syncthreads();

  {
    float qpv = 0.f;
    const int n = ln;
#pragma unroll 2
    for (int c2 = wv * 16; c2 < wv * 16 + 16; c2++)
      for (int hw = 0; hw < 36; hw++)
        qpv = fmaf(act[c2 * 37 + hw], Wet[(c2 * 36 + hw) * 64 + n], qpv);
    qp[wv][n] = qpv;
  }
  __syncthreads();
  if (tid < 64)
    ql[tid] = be[tid] + qp[0][tid] + qp[1][tid] + qp[2][tid] + qp[3][tid];
  __syncthreads();
  if (wv == 0) {
    float s = -INFINITY;
    if (ln < 36) {
      float a = 0.f;
      for (int c = 0; c < 64; c++) a = fmaf(act[c * 37 + ln], ql[c], a);
      s = a;
    }
    float mx = s;
    for (int off = 32; off >= 1; off >>= 1)
      mx = fmaxf(mx, __shfl_xor(mx, off));
    float e = (ln < 36) ? expf(s - mx) : 0.f;
    float sum = e;
    for (int off = 32; off >= 1; off >>= 1) sum += __shfl_xor(sum, off);
    if (ln < 36) sc[ln] = e / sum;
  }
  __syncthreads();
  if (wv == 0) {
    float gv = 0.f;
    for (int hw = 0; hw < 36; hw++) gv = fmaf(act[ln * 37 + hw], sc[hw], gv);
    gm[ln] = gv;
  }
  __syncthreads();
  if (tid < 7) {
    float a = b3[tid];
    for (int c = 0; c < 64; c++) a = fmaf(w3[tid * 64 + c], gm[c], a);
    out[(size_t)(b0 + b) * 7 + tid] = a;
  }
}

// ============================================================================
extern "C" void kernel_launch(void* const* d_in, const int* in_sizes, int n_in,
                              void* d_out, int out_size, void* d_ws,
                              size_t ws_size, hipStream_t stream) {
  const float* x    = (const float*)d_in[0];
  const float* c1w  = (const float*)d_in[1];
  const float* c1b  = (const float*)d_in[2];
  const float* g1   = (const float*)d_in[3];
  const float* bb1  = (const float*)d_in[4];
  const float* m1   = (const float*)d_in[5];
  const float* v1   = (const float*)d_in[6];
  const float* c2w  = (const float*)d_in[7];
  const float* c2b  = (const float*)d_in[8];
  const float* g2   = (const float*)d_in[9];
  const float* bb2  = (const float*)d_in[10];
  const float* m2   = (const float*)d_in[11];
  const float* v2   = (const float*)d_in[12];
  const float* c3w  = (const float*)d_in[13];
  const float* c3b  = (const float*)d_in[14];
  const float* g3   = (const float*)d_in[15];
  const float* bb3  = (const float*)d_in[16];
  const float* m3   = (const float*)d_in[17];
  const float* v3   = (const float*)d_in[18];
  const float* fc1w = (const float*)d_in[19];
  const float* fc1b = (const float*)d_in[20];
  const float* fc2w = (const float*)d_in[21];
  const float* fc2b = (const float*)d_in[22];
  const float* attw = (const float*)d_in[23];
  const float* attb = (const float*)d_in[24];
  const float* fc3w = (const float*)d_in[25];
  const float* fc3b = (const float*)d_in[26];

  const size_t PER_CHUNK = (173056ULL + 25088ULL) * 2;  // bytes per image
  const size_t PERSIST = 589824 + 147456 + 131072 + 589824 + 256 + 8192;
  int CH = 512;
  while (CH > 8 && (size_t)CH * PER_CHUNK + PERSIST > ws_size) CH >>= 1;
  const int NCHK = 512 / CH;

  char* base = (char*)d_ws;
  size_t off = 0;
  auto alloc = [&](size_t nbytes) -> void* {
    void* p = base + off;
    off = (off + nbytes + 255) & ~(size_t)255;
    return p;
  };
  __hip_bfloat16* out1p = (__hip_bfloat16*)alloc((size_t)CH * 173056 * 2);
  __hip_bfloat16* out2p = (__hip_bfloat16*)alloc((size_t)CH * 25088 * 2);
  __hip_bfloat16* wt2  = (__hip_bfloat16*)alloc(589824);
  __hip_bfloat16* wt3  = (__hip_bfloat16*)alloc(147456);
  float* W32           = (float*)alloc(131072);
  float* Wet           = (float*)alloc(589824);
  float* be            = (float*)alloc(256);

  k_prep<<<1569, 256, 0, stream>>>(c2w, wt2, c3w, wt3, attw, fc2w, W32, fc1b,
                                   fc2b, attb, be);

  for (int c = 0; c < NCHK; c++) {
    const float* xc = x + (size_t)c * CH * 2304;
    const int n1 = CH * 4;
    const int grid1 = n1 + (c == 0 ? 576 : 0);  // W_eff fused in chunk 0
    k_conv1<<<grid1, 256, 0, stream>>>(xc, c1w, c1b, g1, bb1, m1, v1, out1p,
                                       out2p, W32, fc1w, Wet, n1);
    k_mconv2<<<CH * 6, 256, 0, stream>>>(out1p, wt2, c2b, g2, bb2, m2, v2,
                                         out2p);
    k_c3attn<<<CH, 256, 0, stream>>>(out2p, wt3, c3b, g3, bb3, m3, v3, Wet, be,
                                     fc3w, fc3b, (float*)d_out, c * CH);
  }
}